// Round 1
// baseline (2200.219 us; speedup 1.0000x reference)
//
#include <hip/hip_runtime.h>
#include <cstdint>
#include <cstddef>
#include <math.h>

// ---------------------------------------------------------------------------
// GATv2 x3 + GraphNorm + ReLU + attentional pooling, fp32 baseline.
// N=16000 nodes, E=256000 edges (+N self loops), H=4 heads.
// ---------------------------------------------------------------------------

#define DEV_INLINE __device__ __forceinline__

DEV_INLINE void atomicMaxFloat(float* addr, float val) {
    // standard bit-punning float atomic max; works for mixed signs:
    // non-negative floats ordered as ints, negative floats reverse-ordered as uints.
    if (val >= 0.f) atomicMax((int*)addr, __float_as_int(val));
    else            atomicMin((unsigned int*)addr, (unsigned int)__float_as_int(val));
}

__global__ void fill_f32(float* __restrict__ p, float v, int n) {
    int t = blockIdx.x * blockDim.x + threadIdx.x;
    if (t < n) p[t] = v;
}

// out[n*HC + c] = bias[c]   (HC power of two -> mask)
__global__ void fill_bias(float* __restrict__ out, const float* __restrict__ bias,
                          int total, int mask) {
    int t = blockIdx.x * blockDim.x + threadIdx.x;
    if (t < total) out[t] = bias[t & mask];
}

// ---------------------------------------------------------------------------
// Simple fp32 tiled GEMM: C[M,Nc] = A[M,K] @ B[K,Nc] (+bias, +relu)
// 64x64 tile, BK=16, 256 threads, 4x4 micro-tile. All dims multiples of 64/16.
// ---------------------------------------------------------------------------
template<bool BIAS, bool RELU>
__global__ __launch_bounds__(256) void gemm_kernel(
        const float* __restrict__ A, const float* __restrict__ Bm,
        const float* __restrict__ bias, float* __restrict__ C,
        int M, int K, int Nc) {
    __shared__ float As[16][65];
    __shared__ float Bs[16][65];
    const int tid = threadIdx.x;
    const int tx = tid & 15;
    const int ty = tid >> 4;
    const int row0 = blockIdx.y * 64;
    const int col0 = blockIdx.x * 64;
    float acc[4][4] = {};

    for (int k0 = 0; k0 < K; k0 += 16) {
        {   // A tile: 64 rows x 16 k, float4 per thread
            int r  = tid >> 2;
            int kk = (tid & 3) * 4;
            const float* ap = A + (size_t)(row0 + r) * K + k0 + kk;
            float4 v = *(const float4*)ap;
            As[kk + 0][r] = v.x; As[kk + 1][r] = v.y;
            As[kk + 2][r] = v.z; As[kk + 3][r] = v.w;
        }
        {   // B tile: 16 k x 64 cols
            int kk = tid >> 4;
            int c  = (tid & 15) * 4;
            const float* bp = Bm + (size_t)(k0 + kk) * Nc + col0 + c;
            float4 v = *(const float4*)bp;
            Bs[kk][c + 0] = v.x; Bs[kk][c + 1] = v.y;
            Bs[kk][c + 2] = v.z; Bs[kk][c + 3] = v.w;
        }
        __syncthreads();
        #pragma unroll
        for (int kk = 0; kk < 16; ++kk) {
            float a[4], b[4];
            #pragma unroll
            for (int i = 0; i < 4; ++i) a[i] = As[kk][ty * 4 + i];
            #pragma unroll
            for (int j = 0; j < 4; ++j) b[j] = Bs[kk][tx * 4 + j];
            #pragma unroll
            for (int i = 0; i < 4; ++i)
                #pragma unroll
                for (int j = 0; j < 4; ++j)
                    acc[i][j] += a[i] * b[j];
        }
        __syncthreads();
    }

    #pragma unroll
    for (int i = 0; i < 4; ++i) {
        int r = row0 + ty * 4 + i;
        #pragma unroll
        for (int j = 0; j < 4; ++j) {
            int c = col0 + tx * 4 + j;
            float v = acc[i][j];
            if (BIAS) v += bias[c];
            if (RELU) v = fmaxf(v, 0.f);
            C[(size_t)r * Nc + c] = v;
        }
    }
}

// ---------------------------------------------------------------------------
// Edge pass A: logit[e,h] = sum_c att[h,c]*leaky_relu(xl[src][h,c]+xr[dst][h,c])
// one wave per edge. Also atomic-max into m[dst,h].
// ---------------------------------------------------------------------------
template<int LOG2C>
__global__ __launch_bounds__(256) void edge_logits(
        const float* __restrict__ xl, const float* __restrict__ xr,
        const float* __restrict__ att,
        const int* __restrict__ esrc, const int* __restrict__ edst,
        int E, int Etot, float* __restrict__ logit, float* __restrict__ m) {
    const int w = (blockIdx.x * blockDim.x + threadIdx.x) >> 6;
    if (w >= Etot) return;
    const int lane = threadIdx.x & 63;
    int src, dst;
    if (w < E) { src = esrc[w]; dst = edst[w]; }
    else       { src = dst = w - E; }
    constexpr int HC = 4 << LOG2C;
    const float* pl = xl + (size_t)src * HC;
    const float* pr = xr + (size_t)dst * HC;
    float acc[4] = {0.f, 0.f, 0.f, 0.f};
    #pragma unroll
    for (int it = 0; it < HC / 64; ++it) {
        int j = lane + it * 64;
        float v = pl[j] + pr[j];
        v = v > 0.f ? v : 0.2f * v;
        acc[j >> LOG2C] += v * att[j];
    }
    #pragma unroll
    for (int h = 0; h < 4; ++h) {
        float a = acc[h];
        #pragma unroll
        for (int s = 32; s; s >>= 1) a += __shfl_xor(a, s);
        if (lane == 0) {
            logit[(size_t)w * 4 + h] = a;
            atomicMaxFloat(&m[dst * 4 + h], a);
        }
    }
}

// ---------------------------------------------------------------------------
// Edge pass B: p = exp(logit - m[dst]); z[dst,h] += p.  One thread per (e,h).
// p overwrites logit in place.
// ---------------------------------------------------------------------------
__global__ void edge_expsum(float* __restrict__ logit,
                            const int* __restrict__ edst, int E, int Etot,
                            const float* __restrict__ m, float* __restrict__ z) {
    int t = blockIdx.x * blockDim.x + threadIdx.x;
    if (t >= Etot * 4) return;
    int e = t >> 2, h = t & 3;
    int dst = (e < E) ? edst[e] : e - E;
    float p = __expf(logit[t] - m[dst * 4 + h]);
    logit[t] = p;
    atomicAdd(&z[dst * 4 + h], p);
}

// ---------------------------------------------------------------------------
// Edge pass C: out[dst,:] += (p[e,h]/(z[dst,h]+1e-16)) * xl[src,:]
// ---------------------------------------------------------------------------
template<int LOG2C>
__global__ __launch_bounds__(256) void edge_scatter(
        const float* __restrict__ xl, const float* __restrict__ p,
        const float* __restrict__ z,
        const int* __restrict__ esrc, const int* __restrict__ edst,
        int E, int Etot, float* __restrict__ out) {
    const int w = (blockIdx.x * blockDim.x + threadIdx.x) >> 6;
    if (w >= Etot) return;
    const int lane = threadIdx.x & 63;
    int src, dst;
    if (w < E) { src = esrc[w]; dst = edst[w]; }
    else       { src = dst = w - E; }
    constexpr int HC = 4 << LOG2C;
    float a[4];
    #pragma unroll
    for (int h = 0; h < 4; ++h)
        a[h] = p[(size_t)w * 4 + h] / (z[dst * 4 + h] + 1e-16f);
    const float* pl = xl + (size_t)src * HC;
    float* po = out + (size_t)dst * HC;
    #pragma unroll
    for (int it = 0; it < HC / 64; ++it) {
        int j = lane + it * 64;
        atomicAdd(&po[j], a[j >> LOG2C] * pl[j]);
    }
}

// ---------------------------------------------------------------------------
// GraphNorm: column sums + sums of squares (one pass), then per-channel affine.
// ---------------------------------------------------------------------------
__global__ __launch_bounds__(64) void colstats(const float* __restrict__ x, int HC,
                                               float* __restrict__ s1, float* __restrict__ s2) {
    int c  = blockIdx.x * 64 + threadIdx.x;
    int r0 = blockIdx.y * 128;
    float a = 0.f, b = 0.f;
    for (int r = r0; r < r0 + 128; ++r) {
        float v = x[(size_t)r * HC + c];
        a += v; b += v * v;
    }
    atomicAdd(&s1[c], a);
    atomicAdd(&s2[c], b);
}

__global__ void gn_finalize(const float* __restrict__ s1, const float* __restrict__ s2,
                            const float* __restrict__ w, const float* __restrict__ b,
                            const float* __restrict__ ms, int HC, float invN,
                            float* __restrict__ alpha, float* __restrict__ beta) {
    int c = blockIdx.x * blockDim.x + threadIdx.x;
    if (c >= HC) return;
    float mean = s1[c] * invN;
    float ex2  = s2[c] * invN;
    float a    = ms[c] * mean;                   // shifted center
    float var  = ex2 - 2.f * a * mean + a * a;   // E[(x-a)^2]
    float al   = w[c] * rsqrtf(var + 1e-5f);
    alpha[c] = al;
    beta[c]  = b[c] - a * al;
}

__global__ void norm_relu(float* __restrict__ x, const float* __restrict__ alpha,
                          const float* __restrict__ beta, int total, int mask) {
    int t = blockIdx.x * blockDim.x + threadIdx.x;
    if (t >= total) return;
    int c = t & mask;
    x[t] = fmaxf(alpha[c] * x[t] + beta[c], 0.f);
}

// ---------------------------------------------------------------------------
// gate[n] = dot(hidden[n,:128], aW2) + ab2   (one wave per node)
// ---------------------------------------------------------------------------
__global__ __launch_bounds__(256) void gate_dot(const float* __restrict__ hid,
                                                const float* __restrict__ aW2,
                                                const float* __restrict__ ab2,
                                                float* __restrict__ gate, int N) {
    int w = (blockIdx.x * blockDim.x + threadIdx.x) >> 6;
    if (w >= N) return;
    int lane = threadIdx.x & 63;
    const float* ph = hid + (size_t)w * 128;
    float a = ph[lane] * aW2[lane] + ph[lane + 64] * aW2[lane + 64];
    #pragma unroll
    for (int s = 32; s; s >>= 1) a += __shfl_xor(a, s);
    if (lane == 0) gate[w] = a + ab2[0];
}

// ---------------------------------------------------------------------------
// Pooling: one block (128 threads) per graph. batch is sorted; binary-search
// the node range, then segment softmax + weighted sum (no atomics).
// ---------------------------------------------------------------------------
__global__ __launch_bounds__(128) void attn_pool(const float* __restrict__ x,
                                                 const float* __restrict__ gate,
                                                 const int* __restrict__ batch,
                                                 int N, float* __restrict__ out) {
    const int b   = blockIdx.x;
    const int tid = threadIdx.x;
    int lo, hi;
    { int l = 0, r = N; while (l < r) { int mid = (l + r) >> 1; if (batch[mid] < b) l = mid + 1; else r = mid; } lo = l; }
    { int l = lo, r = N; while (l < r) { int mid = (l + r) >> 1; if (batch[mid] < b + 1) l = mid + 1; else r = mid; } hi = l; }
    if (lo >= hi) { out[b * 128 + tid] = 0.f; return; }

    __shared__ float red[128];
    float mx = -INFINITY;
    for (int n = lo + tid; n < hi; n += 128) mx = fmaxf(mx, gate[n]);
    red[tid] = mx; __syncthreads();
    for (int s = 64; s; s >>= 1) { if (tid < s) red[tid] = fmaxf(red[tid], red[tid + s]); __syncthreads(); }
    mx = red[0]; __syncthreads();

    float zs = 0.f;
    for (int n = lo + tid; n < hi; n += 128) zs += __expf(gate[n] - mx);
    red[tid] = zs; __syncthreads();
    for (int s = 64; s; s >>= 1) { if (tid < s) red[tid] += red[tid + s]; __syncthreads(); }
    zs = red[0];

    float acc = 0.f;
    for (int n = lo; n < hi; ++n)
        acc += __expf(gate[n] - mx) * x[(size_t)n * 128 + tid];
    out[b * 128 + tid] = acc / (zs + 1e-16f);
}

// ---------------------------------------------------------------------------
extern "C" void kernel_launch(void* const* d_in, const int* in_sizes, int n_in,
                              void* d_out, int out_size, void* d_ws, size_t ws_size,
                              hipStream_t stream) {
    const float* x0  = (const float*)d_in[0];
    const int* edge  = (const int*)d_in[1];
    const int* batch = (const int*)d_in[2];
    const int N = in_sizes[2];
    const int E = in_sizes[1] / 2;
    const int Etot = E + N;
    const int dims[4] = {960, 512, 256, 128};

    const float* Wl[3]   = {(const float*)d_in[3],  (const float*)d_in[10], (const float*)d_in[17]};
    const float* Wr[3]   = {(const float*)d_in[4],  (const float*)d_in[11], (const float*)d_in[18]};
    const float* attp[3] = {(const float*)d_in[5],  (const float*)d_in[12], (const float*)d_in[19]};
    const float* bi[3]   = {(const float*)d_in[6],  (const float*)d_in[13], (const float*)d_in[20]};
    const float* gw[3]   = {(const float*)d_in[7],  (const float*)d_in[14], (const float*)d_in[21]};
    const float* gb[3]   = {(const float*)d_in[8],  (const float*)d_in[15], (const float*)d_in[22]};
    const float* gm[3]   = {(const float*)d_in[9],  (const float*)d_in[16], (const float*)d_in[23]};
    const float* aW1 = (const float*)d_in[24];
    const float* ab1 = (const float*)d_in[25];
    const float* aW2 = (const float*)d_in[26];
    const float* ab2 = (const float*)d_in[27];

    size_t off = 0;
    auto alloc = [&](size_t bytes) -> float* {
        float* p = (float*)((char*)d_ws + off);
        off += (bytes + 255) & ~(size_t)255;
        return p;
    };
    float* bufA  = alloc((size_t)N * 512 * 4);   // xl / gate-hidden
    float* bufB  = alloc((size_t)N * 512 * 4);   // xr
    float* bufC  = alloc((size_t)N * 512 * 4);   // x / layer output
    float* logit = alloc((size_t)Etot * 4 * 4);  // logits -> p
    float* mB    = alloc((size_t)N * 4 * 4);
    float* zB    = alloc((size_t)N * 4 * 4);
    float* s1    = alloc(512 * 4);
    float* s2    = alloc(512 * 4);
    float* alB   = alloc(512 * 4);
    float* beB   = alloc(512 * 4);
    float* gateB = alloc((size_t)N * 4);
    (void)ws_size; (void)n_in; (void)out_size;

    const int egrid = (Etot + 3) / 4;            // 4 waves (edges) per 256-thread block

    for (int l = 0; l < 3; ++l) {
        const int K = dims[l], HC = dims[l + 1];
        const float* xin = (l == 0) ? x0 : bufC;
        dim3 ggrid(HC / 64, N / 64);
        gemm_kernel<false, false><<<ggrid, 256, 0, stream>>>(xin, Wl[l], nullptr, bufA, N, K, HC);
        gemm_kernel<false, false><<<ggrid, 256, 0, stream>>>(xin, Wr[l], nullptr, bufB, N, K, HC);

        fill_f32<<<(N * 4 + 255) / 256, 256, 0, stream>>>(mB, -INFINITY, N * 4);
        hipMemsetAsync(zB, 0, (size_t)N * 4 * sizeof(float), stream);

        if (l == 0)      edge_logits<7><<<egrid, 256, 0, stream>>>(bufA, bufB, attp[l], edge, edge + E, E, Etot, logit, mB);
        else if (l == 1) edge_logits<6><<<egrid, 256, 0, stream>>>(bufA, bufB, attp[l], edge, edge + E, E, Etot, logit, mB);
        else             edge_logits<5><<<egrid, 256, 0, stream>>>(bufA, bufB, attp[l], edge, edge + E, E, Etot, logit, mB);

        edge_expsum<<<(Etot * 4 + 255) / 256, 256, 0, stream>>>(logit, edge + E, E, Etot, mB, zB);

        // out = bias (overwrites xin buffer for l>0: x is dead after the GEMMs)
        fill_bias<<<(N * HC + 255) / 256, 256, 0, stream>>>(bufC, bi[l], N * HC, HC - 1);

        if (l == 0)      edge_scatter<7><<<egrid, 256, 0, stream>>>(bufA, logit, zB, edge, edge + E, E, Etot, bufC);
        else if (l == 1) edge_scatter<6><<<egrid, 256, 0, stream>>>(bufA, logit, zB, edge, edge + E, E, Etot, bufC);
        else             edge_scatter<5><<<egrid, 256, 0, stream>>>(bufA, logit, zB, edge, edge + E, E, Etot, bufC);

        // GraphNorm + ReLU
        hipMemsetAsync(s1, 0, HC * sizeof(float), stream);
        hipMemsetAsync(s2, 0, HC * sizeof(float), stream);
        colstats<<<dim3(HC / 64, N / 128), 64, 0, stream>>>(bufC, HC, s1, s2);
        gn_finalize<<<(HC + 63) / 64, 64, 0, stream>>>(s1, s2, gw[l], gb[l], gm[l], HC, 1.0f / N, alB, beB);
        norm_relu<<<(N * HC + 255) / 256, 256, 0, stream>>>(bufC, alB, beB, N * HC, HC - 1);
    }

    // ---- attentional pooling ----
    gemm_kernel<true, true><<<dim3(2, N / 64), 256, 0, stream>>>(bufC, aW1, ab1, bufA, N, 128, 128);
    gate_dot<<<(N * 64 + 255) / 256, 256, 0, stream>>>(bufA, aW2, ab2, gateB, N);
    attn_pool<<<64, 128, 0, stream>>>(bufC, gateB, batch, N, (float*)d_out);
}

// Round 2
// 1432.744 us; speedup vs baseline: 1.5357x; 1.5357x over previous
//
#include <hip/hip_runtime.h>
#include <cstdint>
#include <cstddef>
#include <math.h>

// ---------------------------------------------------------------------------
// GATv2 x3 + GraphNorm + ReLU + attentional pooling.
// Round 2: dst-CSR + fused gather-based segment-softmax aggregation
// (replaces the atomicAdd scatter that wrote 557 MB/layer to HBM).
// N=16000 nodes, E=256000 edges (+N self loops), H=4 heads.
// ---------------------------------------------------------------------------

// ---------------------------------------------------------------------------
// Simple fp32 tiled GEMM: C[M,Nc] = A[M,K] @ B[K,Nc] (+bias, +relu)
// 64x64 tile, BK=16, 256 threads, 4x4 micro-tile. All dims multiples of 64/16.
// ---------------------------------------------------------------------------
template<bool BIAS, bool RELU>
__global__ __launch_bounds__(256) void gemm_kernel(
        const float* __restrict__ A, const float* __restrict__ Bm,
        const float* __restrict__ bias, float* __restrict__ C,
        int M, int K, int Nc) {
    __shared__ float As[16][65];
    __shared__ float Bs[16][65];
    const int tid = threadIdx.x;
    const int tx = tid & 15;
    const int ty = tid >> 4;
    const int row0 = blockIdx.y * 64;
    const int col0 = blockIdx.x * 64;
    float acc[4][4] = {};

    for (int k0 = 0; k0 < K; k0 += 16) {
        {   // A tile: 64 rows x 16 k, float4 per thread
            int r  = tid >> 2;
            int kk = (tid & 3) * 4;
            const float* ap = A + (size_t)(row0 + r) * K + k0 + kk;
            float4 v = *(const float4*)ap;
            As[kk + 0][r] = v.x; As[kk + 1][r] = v.y;
            As[kk + 2][r] = v.z; As[kk + 3][r] = v.w;
        }
        {   // B tile: 16 k x 64 cols
            int kk = tid >> 4;
            int c  = (tid & 15) * 4;
            const float* bp = Bm + (size_t)(k0 + kk) * Nc + col0 + c;
            float4 v = *(const float4*)bp;
            Bs[kk][c + 0] = v.x; Bs[kk][c + 1] = v.y;
            Bs[kk][c + 2] = v.z; Bs[kk][c + 3] = v.w;
        }
        __syncthreads();
        #pragma unroll
        for (int kk = 0; kk < 16; ++kk) {
            float a[4], b[4];
            #pragma unroll
            for (int i = 0; i < 4; ++i) a[i] = As[kk][ty * 4 + i];
            #pragma unroll
            for (int j = 0; j < 4; ++j) b[j] = Bs[kk][tx * 4 + j];
            #pragma unroll
            for (int i = 0; i < 4; ++i)
                #pragma unroll
                for (int j = 0; j < 4; ++j)
                    acc[i][j] += a[i] * b[j];
        }
        __syncthreads();
    }

    #pragma unroll
    for (int i = 0; i < 4; ++i) {
        int r = row0 + ty * 4 + i;
        #pragma unroll
        for (int j = 0; j < 4; ++j) {
            int c = col0 + tx * 4 + j;
            float v = acc[i][j];
            if (BIAS) v += bias[c];
            if (RELU) v = fmaxf(v, 0.f);
            C[(size_t)r * Nc + c] = v;
        }
    }
}

// ---------------------------------------------------------------------------
// CSR build (once per call; edge_index is layer-invariant).
// ---------------------------------------------------------------------------
__global__ void csr_count(const int* __restrict__ edst, int E, int Etot,
                          int* __restrict__ deg) {
    int e = blockIdx.x * blockDim.x + threadIdx.x;
    if (e >= Etot) return;
    int d = (e < E) ? edst[e] : e - E;     // self-loop tail: dst = node id
    atomicAdd(&deg[d], 1);
}

// single-block inclusive scan -> row_start[0..N], row_start[0]=0
__global__ __launch_bounds__(1024) void scan_deg(const int* __restrict__ deg,
                                                 int* __restrict__ row_start, int N) {
    __shared__ int sh[1024];
    const int tid = threadIdx.x;
    int carry = 0;
    for (int base = 0; base < N; base += 1024) {
        int i = base + tid;
        sh[tid] = (i < N) ? deg[i] : 0;
        __syncthreads();
        #pragma unroll
        for (int off = 1; off < 1024; off <<= 1) {
            int t = (tid >= off) ? sh[tid - off] : 0;
            __syncthreads();
            sh[tid] += t;
            __syncthreads();
        }
        if (i < N) row_start[i + 1] = carry + sh[tid];
        carry += sh[1023];
        __syncthreads();
    }
    if (tid == 0) row_start[0] = 0;
}

__global__ void csr_fill(const int* __restrict__ esrc, const int* __restrict__ edst,
                         int E, int Etot, int* __restrict__ cursor,
                         int* __restrict__ src_perm) {
    int e = blockIdx.x * blockDim.x + threadIdx.x;
    if (e >= Etot) return;
    int s, d;
    if (e < E) { s = esrc[e]; d = edst[e]; }
    else       { s = d = e - E; }
    int pos = atomicAdd(&cursor[d], 1);
    src_perm[pos] = s;
}

// ---------------------------------------------------------------------------
// Fused GATv2 edge phase, gather form. One wave per dst node.
// Chunked online softmax (CAP edges/chunk) so any degree is handled.
// out[dst, :] = sum_e alpha[e,h] * xl[src_e, :]  + bias   (alpha = softmax)
// ---------------------------------------------------------------------------
template<int LOG2C>
__global__ __launch_bounds__(256) void gat_agg(
        const float* __restrict__ xl, const float* __restrict__ xr,
        const float* __restrict__ att, const float* __restrict__ bias,
        const int* __restrict__ row_start, const int* __restrict__ src_perm,
        int N, float* __restrict__ out) {
    constexpr int HC  = 4 << LOG2C;     // 512 / 256 / 128
    constexpr int REG = HC / 64;        // 8 / 4 / 2
    constexpr int CAP = 128;            // edges per chunk (degree ~17 here)
    __shared__ float lg[4][CAP * 4];

    const int widx = threadIdx.x >> 6;
    const int lane = threadIdx.x & 63;
    const int dst  = blockIdx.x * 4 + widx;
    if (dst >= N) return;

    const int start = row_start[dst];
    const int end   = row_start[dst + 1];  // >= start+1 (self-loop)

    float xrv[REG], attv[REG], acc[REG];
    #pragma unroll
    for (int it = 0; it < REG; ++it) {
        int j = lane + it * 64;
        xrv[it]  = xr[(size_t)dst * HC + j];
        attv[it] = att[j];
        acc[it]  = 0.f;
    }
    float m0 = -INFINITY, m1 = -INFINITY, m2 = -INFINITY, m3 = -INFINITY;
    float z0 = 0.f, z1 = 0.f, z2 = 0.f, z3 = 0.f;

    for (int cs = start; cs < end; cs += CAP) {
        const int cnt = min(CAP, end - cs);
        float c0 = -INFINITY, c1 = -INFINITY, c2 = -INFINITY, c3 = -INFINITY;

        // ---- pass 1: logits for this chunk -> LDS, track chunk max ----
        for (int k = 0; k < cnt; ++k) {
            int src = __builtin_amdgcn_readfirstlane(src_perm[cs + k]);
            const float* px = xl + (size_t)src * HC;
            float a0 = 0.f, a1 = 0.f, a2 = 0.f, a3 = 0.f;
            #pragma unroll
            for (int it = 0; it < REG; ++it) {
                int j = lane + it * 64;
                float v = px[j] + xrv[it];
                v = v > 0.f ? v : 0.2f * v;      // leaky_relu(0.2)
                v *= attv[it];
                if constexpr (LOG2C >= 6) {
                    constexpr int dummy = 0; (void)dummy;
                    const int h = (it * 64) >> LOG2C;   // compile-time per it
                    if (h == 0) a0 += v; else if (h == 1) a1 += v;
                    else if (h == 2) a2 += v; else a3 += v;
                } else {  // HC=128: head = (lane>>5) + 2*it
                    if (lane < 32) { if (it == 0) a0 += v; else a2 += v; }
                    else           { if (it == 0) a1 += v; else a3 += v; }
                }
            }
            #pragma unroll
            for (int s = 32; s; s >>= 1) {
                a0 += __shfl_xor(a0, s);
                a1 += __shfl_xor(a1, s);
                a2 += __shfl_xor(a2, s);
                a3 += __shfl_xor(a3, s);
            }
            c0 = fmaxf(c0, a0); c1 = fmaxf(c1, a1);
            c2 = fmaxf(c2, a2); c3 = fmaxf(c3, a3);
            if (lane == 0) {
                lg[widx][k * 4 + 0] = a0; lg[widx][k * 4 + 1] = a1;
                lg[widx][k * 4 + 2] = a2; lg[widx][k * 4 + 3] = a3;
            }
        }

        // ---- merge chunk max into running state (first chunk: exp(-inf)=0) ----
        float n0 = fmaxf(m0, c0), n1 = fmaxf(m1, c1);
        float n2 = fmaxf(m2, c2), n3 = fmaxf(m3, c3);
        float s0 = __expf(m0 - n0), s1 = __expf(m1 - n1);
        float s2 = __expf(m2 - n2), s3 = __expf(m3 - n3);
        z0 *= s0; z1 *= s1; z2 *= s2; z3 *= s3;
        #pragma unroll
        for (int it = 0; it < REG; ++it) {
            float sc;
            if constexpr (LOG2C >= 6) {
                const int h = (it * 64) >> LOG2C;
                sc = h == 0 ? s0 : h == 1 ? s1 : h == 2 ? s2 : s3;
            } else {
                sc = (lane < 32) ? (it == 0 ? s0 : s2) : (it == 0 ? s1 : s3);
            }
            acc[it] *= sc;
        }
        m0 = n0; m1 = n1; m2 = n2; m3 = n3;

        // ---- pass 2: p = exp(logit - m); z += p; acc += p * xl[src] ----
        for (int k = 0; k < cnt; ++k) {
            int src = __builtin_amdgcn_readfirstlane(src_perm[cs + k]);
            const float* px = xl + (size_t)src * HC;
            float p0 = __expf(lg[widx][k * 4 + 0] - m0);
            float p1 = __expf(lg[widx][k * 4 + 1] - m1);
            float p2 = __expf(lg[widx][k * 4 + 2] - m2);
            float p3 = __expf(lg[widx][k * 4 + 3] - m3);
            z0 += p0; z1 += p1; z2 += p2; z3 += p3;
            #pragma unroll
            for (int it = 0; it < REG; ++it) {
                int j = lane + it * 64;
                float p;
                if constexpr (LOG2C >= 6) {
                    const int h = (it * 64) >> LOG2C;
                    p = h == 0 ? p0 : h == 1 ? p1 : h == 2 ? p2 : p3;
                } else {
                    p = (lane < 32) ? (it == 0 ? p0 : p2) : (it == 0 ? p1 : p3);
                }
                acc[it] += p * px[j];
            }
        }
    }

    #pragma unroll
    for (int it = 0; it < REG; ++it) {
        int j = lane + it * 64;
        float z;
        if constexpr (LOG2C >= 6) {
            const int h = (it * 64) >> LOG2C;
            z = h == 0 ? z0 : h == 1 ? z1 : h == 2 ? z2 : z3;
        } else {
            z = (lane < 32) ? (it == 0 ? z0 : z2) : (it == 0 ? z1 : z3);
        }
        out[(size_t)dst * HC + j] = acc[it] / (z + 1e-16f) + bias[j];
    }
}

// ---------------------------------------------------------------------------
// GraphNorm: column sums + sums of squares (one pass), then per-channel affine.
// ---------------------------------------------------------------------------
__global__ __launch_bounds__(64) void colstats(const float* __restrict__ x, int HC,
                                               float* __restrict__ s1, float* __restrict__ s2) {
    int c  = blockIdx.x * 64 + threadIdx.x;
    int r0 = blockIdx.y * 128;
    float a = 0.f, b = 0.f;
    for (int r = r0; r < r0 + 128; ++r) {
        float v = x[(size_t)r * HC + c];
        a += v; b += v * v;
    }
    atomicAdd(&s1[c], a);
    atomicAdd(&s2[c], b);
}

__global__ void gn_finalize(const float* __restrict__ s1, const float* __restrict__ s2,
                            const float* __restrict__ w, const float* __restrict__ b,
                            const float* __restrict__ ms, int HC, float invN,
                            float* __restrict__ alpha, float* __restrict__ beta) {
    int c = blockIdx.x * blockDim.x + threadIdx.x;
    if (c >= HC) return;
    float mean = s1[c] * invN;
    float ex2  = s2[c] * invN;
    float a    = ms[c] * mean;                   // shifted center
    float var  = ex2 - 2.f * a * mean + a * a;   // E[(x-a)^2]
    float al   = w[c] * rsqrtf(var + 1e-5f);
    alpha[c] = al;
    beta[c]  = b[c] - a * al;
}

__global__ void norm_relu(float* __restrict__ x, const float* __restrict__ alpha,
                          const float* __restrict__ beta, int total, int mask) {
    int t = blockIdx.x * blockDim.x + threadIdx.x;
    if (t >= total) return;
    int c = t & mask;
    x[t] = fmaxf(alpha[c] * x[t] + beta[c], 0.f);
}

// ---------------------------------------------------------------------------
// gate[n] = dot(hidden[n,:128], aW2) + ab2   (one wave per node)
// ---------------------------------------------------------------------------
__global__ __launch_bounds__(256) void gate_dot(const float* __restrict__ hid,
                                                const float* __restrict__ aW2,
                                                const float* __restrict__ ab2,
                                                float* __restrict__ gate, int N) {
    int w = (blockIdx.x * blockDim.x + threadIdx.x) >> 6;
    if (w >= N) return;
    int lane = threadIdx.x & 63;
    const float* ph = hid + (size_t)w * 128;
    float a = ph[lane] * aW2[lane] + ph[lane + 64] * aW2[lane + 64];
    #pragma unroll
    for (int s = 32; s; s >>= 1) a += __shfl_xor(a, s);
    if (lane == 0) gate[w] = a + ab2[0];
}

// ---------------------------------------------------------------------------
// Pooling: one block (128 threads) per graph. batch is sorted; binary-search
// the node range, then segment softmax + weighted sum (no atomics).
// ---------------------------------------------------------------------------
__global__ __launch_bounds__(128) void attn_pool(const float* __restrict__ x,
                                                 const float* __restrict__ gate,
                                                 const int* __restrict__ batch,
                                                 int N, float* __restrict__ out) {
    const int b   = blockIdx.x;
    const int tid = threadIdx.x;
    int lo, hi;
    { int l = 0, r = N; while (l < r) { int mid = (l + r) >> 1; if (batch[mid] < b) l = mid + 1; else r = mid; } lo = l; }
    { int l = lo, r = N; while (l < r) { int mid = (l + r) >> 1; if (batch[mid] < b + 1) l = mid + 1; else r = mid; } hi = l; }
    if (lo >= hi) { out[b * 128 + tid] = 0.f; return; }

    __shared__ float red[128];
    float mx = -INFINITY;
    for (int n = lo + tid; n < hi; n += 128) mx = fmaxf(mx, gate[n]);
    red[tid] = mx; __syncthreads();
    for (int s = 64; s; s >>= 1) { if (tid < s) red[tid] = fmaxf(red[tid], red[tid + s]); __syncthreads(); }
    mx = red[0]; __syncthreads();

    float zs = 0.f;
    for (int n = lo + tid; n < hi; n += 128) zs += __expf(gate[n] - mx);
    red[tid] = zs; __syncthreads();
    for (int s = 64; s; s >>= 1) { if (tid < s) red[tid] += red[tid + s]; __syncthreads(); }
    zs = red[0];

    float acc = 0.f;
    for (int n = lo; n < hi; ++n)
        acc += __expf(gate[n] - mx) * x[(size_t)n * 128 + tid];
    out[b * 128 + tid] = acc / (zs + 1e-16f);
}

// ---------------------------------------------------------------------------
extern "C" void kernel_launch(void* const* d_in, const int* in_sizes, int n_in,
                              void* d_out, int out_size, void* d_ws, size_t ws_size,
                              hipStream_t stream) {
    const float* x0  = (const float*)d_in[0];
    const int* edge  = (const int*)d_in[1];
    const int* batch = (const int*)d_in[2];
    const int N = in_sizes[2];
    const int E = in_sizes[1] / 2;
    const int Etot = E + N;
    const int dims[4] = {960, 512, 256, 128};

    const float* Wl[3]   = {(const float*)d_in[3],  (const float*)d_in[10], (const float*)d_in[17]};
    const float* Wr[3]   = {(const float*)d_in[4],  (const float*)d_in[11], (const float*)d_in[18]};
    const float* attp[3] = {(const float*)d_in[5],  (const float*)d_in[12], (const float*)d_in[19]};
    const float* bi[3]   = {(const float*)d_in[6],  (const float*)d_in[13], (const float*)d_in[20]};
    const float* gw[3]   = {(const float*)d_in[7],  (const float*)d_in[14], (const float*)d_in[21]};
    const float* gb[3]   = {(const float*)d_in[8],  (const float*)d_in[15], (const float*)d_in[22]};
    const float* gm[3]   = {(const float*)d_in[9],  (const float*)d_in[16], (const float*)d_in[23]};
    const float* aW1 = (const float*)d_in[24];
    const float* ab1 = (const float*)d_in[25];
    const float* aW2 = (const float*)d_in[26];
    const float* ab2 = (const float*)d_in[27];

    size_t off = 0;
    auto alloc = [&](size_t bytes) -> char* {
        char* p = (char*)d_ws + off;
        off += (bytes + 255) & ~(size_t)255;
        return p;
    };
    float* bufA      = (float*)alloc((size_t)N * 512 * 4);   // xl / gate-hidden
    float* bufB      = (float*)alloc((size_t)N * 512 * 4);   // xr
    float* bufC      = (float*)alloc((size_t)N * 512 * 4);   // x / layer output
    int*   deg       = (int*)alloc((size_t)N * 4);
    int*   row_start = (int*)alloc((size_t)(N + 1) * 4);
    int*   cursor    = (int*)alloc((size_t)N * 4);
    int*   src_perm  = (int*)alloc((size_t)Etot * 4);
    float* s1        = (float*)alloc(512 * 4);
    float* s2        = (float*)alloc(512 * 4);
    float* alB       = (float*)alloc(512 * 4);
    float* beB       = (float*)alloc(512 * 4);
    float* gateB     = (float*)alloc((size_t)N * 4);
    (void)ws_size; (void)n_in; (void)out_size;

    // ---- CSR by dst (edge_index is the same for all layers) ----
    hipMemsetAsync(deg, 0, (size_t)N * sizeof(int), stream);
    csr_count<<<(Etot + 255) / 256, 256, 0, stream>>>(edge + E, E, Etot, deg);
    scan_deg<<<1, 1024, 0, stream>>>(deg, row_start, N);
    hipMemcpyAsync(cursor, row_start, (size_t)N * sizeof(int),
                   hipMemcpyDeviceToDevice, stream);
    csr_fill<<<(Etot + 255) / 256, 256, 0, stream>>>(edge, edge + E, E, Etot,
                                                     cursor, src_perm);

    for (int l = 0; l < 3; ++l) {
        const int K = dims[l], HC = dims[l + 1];
        const float* xin = (l == 0) ? x0 : bufC;
        dim3 ggrid(HC / 64, N / 64);
        gemm_kernel<false, false><<<ggrid, 256, 0, stream>>>(xin, Wl[l], nullptr, bufA, N, K, HC);
        gemm_kernel<false, false><<<ggrid, 256, 0, stream>>>(xin, Wr[l], nullptr, bufB, N, K, HC);

        // fused edge softmax + aggregation (overwrites bufC; xin dead after GEMMs)
        const int agrid = (N + 3) / 4;
        if (l == 0)      gat_agg<7><<<agrid, 256, 0, stream>>>(bufA, bufB, attp[l], bi[l], row_start, src_perm, N, bufC);
        else if (l == 1) gat_agg<6><<<agrid, 256, 0, stream>>>(bufA, bufB, attp[l], bi[l], row_start, src_perm, N, bufC);
        else             gat_agg<5><<<agrid, 256, 0, stream>>>(bufA, bufB, attp[l], bi[l], row_start, src_perm, N, bufC);

        // GraphNorm + ReLU
        hipMemsetAsync(s1, 0, HC * sizeof(float), stream);
        hipMemsetAsync(s2, 0, HC * sizeof(float), stream);
        colstats<<<dim3(HC / 64, N / 128), 64, 0, stream>>>(bufC, HC, s1, s2);
        gn_finalize<<<(HC + 63) / 64, 64, 0, stream>>>(s1, s2, gw[l], gb[l], gm[l], HC, 1.0f / N, alB, beB);
        norm_relu<<<(N * HC + 255) / 256, 256, 0, stream>>>(bufC, alB, beB, N * HC, HC - 1);
    }

    // ---- attentional pooling ----
    gemm_kernel<true, true><<<dim3(2, N / 64), 256, 0, stream>>>(bufC, aW1, ab1, bufA, N, 128, 128);
    gate_dot<<<(N * 64 + 255) / 256, 256, 0, stream>>>(bufA, aW2, ab2, gateB, N);
    attn_pool<<<64, 128, 0, stream>>>(bufC, gateB, batch, N, (float*)d_out);
}

// Round 3
// 821.289 us; speedup vs baseline: 2.6790x; 1.7445x over previous
//
#include <hip/hip_runtime.h>
#include <cstdint>
#include <cstddef>
#include <math.h>

// ---------------------------------------------------------------------------
// GATv2 x3 + GraphNorm + ReLU + attentional pooling.
// Round 3: GEMMs moved to bf16 MFMA with bf16x3 split (fp32-accurate):
//   A@B ~= Ahi@Bhi + Ahi@Blo + Alo@Bhi   (error ~2^-17, numerically fp32)
// A is split on the fly during LDS staging; weights pre-transposed/split once.
// ---------------------------------------------------------------------------

typedef __bf16 bf16x8 __attribute__((ext_vector_type(8)));
typedef float  f32x4  __attribute__((ext_vector_type(4)));

// ---------------------------------------------------------------------------
// Weight conversion: W [K][N] fp32 -> Wt_hi/lo [N][K] bf16 (transposed, split)
// ---------------------------------------------------------------------------
__global__ void conv_w(const float* __restrict__ W, __bf16* __restrict__ Whi,
                       __bf16* __restrict__ Wlo, int K, int N) {
    int t = blockIdx.x * blockDim.x + threadIdx.x;
    if (t >= K * N) return;
    int k = t / N, n = t - k * N;
    float v = W[t];
    __bf16 h = (__bf16)v;
    Whi[(size_t)n * K + k] = h;
    Wlo[(size_t)n * K + k] = (__bf16)(v - (float)h);
}

// ---------------------------------------------------------------------------
// MFMA GEMM: C[M,N] = A[M,K](fp32) @ Bt[N,K](bf16 hi/lo, pre-transposed)
// 128x128 tile, 4 waves (2x2), each wave 64x64 = 4x4 frags of 16x16x32.
// A split into bf16 hi/lo during staging. M%128==0, N%128==0, K%32==0.
// ---------------------------------------------------------------------------
template<bool BIAS, bool RELU>
__global__ __launch_bounds__(256) void mfma_gemm(
        const float* __restrict__ A,
        const __bf16* __restrict__ Bthi, const __bf16* __restrict__ Btlo,
        const float* __restrict__ bias, float* __restrict__ C,
        int M, int K, int N) {
    __shared__ __attribute__((aligned(16))) __bf16 sAh[128 * 32];
    __shared__ __attribute__((aligned(16))) __bf16 sAl[128 * 32];
    __shared__ __attribute__((aligned(16))) __bf16 sBh[128 * 32];
    __shared__ __attribute__((aligned(16))) __bf16 sBl[128 * 32];

    const int tid  = threadIdx.x;
    const int row0 = blockIdx.y * 128;
    const int col0 = blockIdx.x * 128;
    const int lane = tid & 63;
    const int w    = tid >> 6;
    const int wm   = w >> 1, wn = w & 1;
    const int lr   = lane & 15, lg = lane >> 4;
    const int sr   = tid >> 2;            // staging row 0..63
    const int sc   = (tid & 3) * 8;       // staging k-chunk {0,8,16,24}

    f32x4 acc[4][4] = {};

    for (int k0 = 0; k0 < K; k0 += 32) {
        #pragma unroll
        for (int half = 0; half < 2; ++half) {
            const int rr = sr + half * 64;
            // ---- A: fp32 -> split bf16 hi/lo ----
            const float* src = A + (size_t)(row0 + rr) * K + k0 + sc;
            float4 u0 = *(const float4*)src;
            float4 u1 = *(const float4*)(src + 4);
            float uu[8] = {u0.x, u0.y, u0.z, u0.w, u1.x, u1.y, u1.z, u1.w};
            bf16x8 h, lo;
            #pragma unroll
            for (int j = 0; j < 8; ++j) {
                __bf16 hh = (__bf16)uu[j];
                h[j]  = hh;
                lo[j] = (__bf16)(uu[j] - (float)hh);
            }
            *(bf16x8*)&sAh[rr * 32 + sc] = h;
            *(bf16x8*)&sAl[rr * 32 + sc] = lo;
            // ---- B: bf16 direct copy ----
            *(bf16x8*)&sBh[rr * 32 + sc] =
                *(const bf16x8*)(Bthi + (size_t)(col0 + rr) * K + k0 + sc);
            *(bf16x8*)&sBl[rr * 32 + sc] =
                *(const bf16x8*)(Btlo + (size_t)(col0 + rr) * K + k0 + sc);
        }
        __syncthreads();

        bf16x8 ah[4], al[4], bh[4], bl[4];
        #pragma unroll
        for (int i = 0; i < 4; ++i) {
            const int ar = (wm * 64 + i * 16 + lr) * 32 + lg * 8;
            const int bc = (wn * 64 + i * 16 + lr) * 32 + lg * 8;
            ah[i] = *(const bf16x8*)&sAh[ar];
            al[i] = *(const bf16x8*)&sAl[ar];
            bh[i] = *(const bf16x8*)&sBh[bc];
            bl[i] = *(const bf16x8*)&sBl[bc];
        }
        #pragma unroll
        for (int i = 0; i < 4; ++i)
            #pragma unroll
            for (int j = 0; j < 4; ++j) {
                acc[i][j] = __builtin_amdgcn_mfma_f32_16x16x32_bf16(ah[i], bh[j], acc[i][j], 0, 0, 0);
                acc[i][j] = __builtin_amdgcn_mfma_f32_16x16x32_bf16(ah[i], bl[j], acc[i][j], 0, 0, 0);
                acc[i][j] = __builtin_amdgcn_mfma_f32_16x16x32_bf16(al[i], bh[j], acc[i][j], 0, 0, 0);
            }
        __syncthreads();
    }

    #pragma unroll
    for (int i = 0; i < 4; ++i) {
        const int rowb = row0 + wm * 64 + i * 16 + lg * 4;
        #pragma unroll
        for (int j = 0; j < 4; ++j) {
            const int col = col0 + wn * 64 + j * 16 + lr;
            const float bv = BIAS ? bias[col] : 0.f;
            #pragma unroll
            for (int q = 0; q < 4; ++q) {
                float v = acc[i][j][q] + bv;
                if (RELU) v = fmaxf(v, 0.f);
                C[(size_t)(rowb + q) * N + col] = v;
            }
        }
    }
}

// ---------------------------------------------------------------------------
// CSR build (once per call; edge_index is layer-invariant).
// ---------------------------------------------------------------------------
__global__ void csr_count(const int* __restrict__ edst, int E, int Etot,
                          int* __restrict__ deg) {
    int e = blockIdx.x * blockDim.x + threadIdx.x;
    if (e >= Etot) return;
    int d = (e < E) ? edst[e] : e - E;
    atomicAdd(&deg[d], 1);
}

__global__ __launch_bounds__(1024) void scan_deg(const int* __restrict__ deg,
                                                 int* __restrict__ row_start, int N) {
    __shared__ int sh[1024];
    const int tid = threadIdx.x;
    int carry = 0;
    for (int base = 0; base < N; base += 1024) {
        int i = base + tid;
        sh[tid] = (i < N) ? deg[i] : 0;
        __syncthreads();
        #pragma unroll
        for (int off = 1; off < 1024; off <<= 1) {
            int t = (tid >= off) ? sh[tid - off] : 0;
            __syncthreads();
            sh[tid] += t;
            __syncthreads();
        }
        if (i < N) row_start[i + 1] = carry + sh[tid];
        carry += sh[1023];
        __syncthreads();
    }
    if (tid == 0) row_start[0] = 0;
}

__global__ void csr_fill(const int* __restrict__ esrc, const int* __restrict__ edst,
                         int E, int Etot, int* __restrict__ cursor,
                         int* __restrict__ src_perm) {
    int e = blockIdx.x * blockDim.x + threadIdx.x;
    if (e >= Etot) return;
    int s, d;
    if (e < E) { s = esrc[e]; d = edst[e]; }
    else       { s = d = e - E; }
    int pos = atomicAdd(&cursor[d], 1);
    src_perm[pos] = s;
}

// ---------------------------------------------------------------------------
// Fused GATv2 edge phase, gather form. One wave per dst node.
// ---------------------------------------------------------------------------
template<int LOG2C>
__global__ __launch_bounds__(256) void gat_agg(
        const float* __restrict__ xl, const float* __restrict__ xr,
        const float* __restrict__ att, const float* __restrict__ bias,
        const int* __restrict__ row_start, const int* __restrict__ src_perm,
        int N, float* __restrict__ out) {
    constexpr int HC  = 4 << LOG2C;     // 512 / 256 / 128
    constexpr int REG = HC / 64;        // 8 / 4 / 2
    constexpr int CAP = 128;
    __shared__ float lg[4][CAP * 4];

    const int widx = threadIdx.x >> 6;
    const int lane = threadIdx.x & 63;
    const int dst  = blockIdx.x * 4 + widx;
    if (dst >= N) return;

    const int start = row_start[dst];
    const int end   = row_start[dst + 1];

    float xrv[REG], attv[REG], acc[REG];
    #pragma unroll
    for (int it = 0; it < REG; ++it) {
        int j = lane + it * 64;
        xrv[it]  = xr[(size_t)dst * HC + j];
        attv[it] = att[j];
        acc[it]  = 0.f;
    }
    float m0 = -INFINITY, m1 = -INFINITY, m2 = -INFINITY, m3 = -INFINITY;
    float z0 = 0.f, z1 = 0.f, z2 = 0.f, z3 = 0.f;

    for (int cs = start; cs < end; cs += CAP) {
        const int cnt = min(CAP, end - cs);
        float c0 = -INFINITY, c1 = -INFINITY, c2 = -INFINITY, c3 = -INFINITY;

        for (int k = 0; k < cnt; ++k) {
            int src = __builtin_amdgcn_readfirstlane(src_perm[cs + k]);
            const float* px = xl + (size_t)src * HC;
            float a0 = 0.f, a1 = 0.f, a2 = 0.f, a3 = 0.f;
            #pragma unroll
            for (int it = 0; it < REG; ++it) {
                int j = lane + it * 64;
                float v = px[j] + xrv[it];
                v = v > 0.f ? v : 0.2f * v;
                v *= attv[it];
                if constexpr (LOG2C >= 6) {
                    const int h = (it * 64) >> LOG2C;
                    if (h == 0) a0 += v; else if (h == 1) a1 += v;
                    else if (h == 2) a2 += v; else a3 += v;
                } else {
                    if (lane < 32) { if (it == 0) a0 += v; else a2 += v; }
                    else           { if (it == 0) a1 += v; else a3 += v; }
                }
            }
            #pragma unroll
            for (int s = 32; s; s >>= 1) {
                a0 += __shfl_xor(a0, s);
                a1 += __shfl_xor(a1, s);
                a2 += __shfl_xor(a2, s);
                a3 += __shfl_xor(a3, s);
            }
            c0 = fmaxf(c0, a0); c1 = fmaxf(c1, a1);
            c2 = fmaxf(c2, a2); c3 = fmaxf(c3, a3);
            if (lane == 0) {
                lg[widx][k * 4 + 0] = a0; lg[widx][k * 4 + 1] = a1;
                lg[widx][k * 4 + 2] = a2; lg[widx][k * 4 + 3] = a3;
            }
        }

        float n0 = fmaxf(m0, c0), n1 = fmaxf(m1, c1);
        float n2 = fmaxf(m2, c2), n3 = fmaxf(m3, c3);
        float s0 = __expf(m0 - n0), s1 = __expf(m1 - n1);
        float s2 = __expf(m2 - n2), s3 = __expf(m3 - n3);
        z0 *= s0; z1 *= s1; z2 *= s2; z3 *= s3;
        #pragma unroll
        for (int it = 0; it < REG; ++it) {
            float scv;
            if constexpr (LOG2C >= 6) {
                const int h = (it * 64) >> LOG2C;
                scv = h == 0 ? s0 : h == 1 ? s1 : h == 2 ? s2 : s3;
            } else {
                scv = (lane < 32) ? (it == 0 ? s0 : s2) : (it == 0 ? s1 : s3);
            }
            acc[it] *= scv;
        }
        m0 = n0; m1 = n1; m2 = n2; m3 = n3;

        for (int k = 0; k < cnt; ++k) {
            int src = __builtin_amdgcn_readfirstlane(src_perm[cs + k]);
            const float* px = xl + (size_t)src * HC;
            float p0 = __expf(lg[widx][k * 4 + 0] - m0);
            float p1 = __expf(lg[widx][k * 4 + 1] - m1);
            float p2 = __expf(lg[widx][k * 4 + 2] - m2);
            float p3 = __expf(lg[widx][k * 4 + 3] - m3);
            z0 += p0; z1 += p1; z2 += p2; z3 += p3;
            #pragma unroll
            for (int it = 0; it < REG; ++it) {
                int j = lane + it * 64;
                float p;
                if constexpr (LOG2C >= 6) {
                    const int h = (it * 64) >> LOG2C;
                    p = h == 0 ? p0 : h == 1 ? p1 : h == 2 ? p2 : p3;
                } else {
                    p = (lane < 32) ? (it == 0 ? p0 : p2) : (it == 0 ? p1 : p3);
                }
                acc[it] += p * px[j];
            }
        }
    }

    #pragma unroll
    for (int it = 0; it < REG; ++it) {
        int j = lane + it * 64;
        float z;
        if constexpr (LOG2C >= 6) {
            const int h = (it * 64) >> LOG2C;
            z = h == 0 ? z0 : h == 1 ? z1 : h == 2 ? z2 : z3;
        } else {
            z = (lane < 32) ? (it == 0 ? z0 : z2) : (it == 0 ? z1 : z3);
        }
        out[(size_t)dst * HC + j] = acc[it] / (z + 1e-16f) + bias[j];
    }
}

// ---------------------------------------------------------------------------
// GraphNorm + ReLU
// ---------------------------------------------------------------------------
__global__ __launch_bounds__(64) void colstats(const float* __restrict__ x, int HC,
                                               float* __restrict__ s1, float* __restrict__ s2) {
    int c  = blockIdx.x * 64 + threadIdx.x;
    int r0 = blockIdx.y * 128;
    float a = 0.f, b = 0.f;
    for (int r = r0; r < r0 + 128; ++r) {
        float v = x[(size_t)r * HC + c];
        a += v; b += v * v;
    }
    atomicAdd(&s1[c], a);
    atomicAdd(&s2[c], b);
}

__global__ void gn_finalize(const float* __restrict__ s1, const float* __restrict__ s2,
                            const float* __restrict__ w, const float* __restrict__ b,
                            const float* __restrict__ ms, int HC, float invN,
                            float* __restrict__ alpha, float* __restrict__ beta) {
    int c = blockIdx.x * blockDim.x + threadIdx.x;
    if (c >= HC) return;
    float mean = s1[c] * invN;
    float ex2  = s2[c] * invN;
    float a    = ms[c] * mean;
    float var  = ex2 - 2.f * a * mean + a * a;
    float al   = w[c] * rsqrtf(var + 1e-5f);
    alpha[c] = al;
    beta[c]  = b[c] - a * al;
}

__global__ void norm_relu(float* __restrict__ x, const float* __restrict__ alpha,
                          const float* __restrict__ beta, int total, int mask) {
    int t = blockIdx.x * blockDim.x + threadIdx.x;
    if (t >= total) return;
    int c = t & mask;
    x[t] = fmaxf(alpha[c] * x[t] + beta[c], 0.f);
}

// ---------------------------------------------------------------------------
__global__ __launch_bounds__(256) void gate_dot(const float* __restrict__ hid,
                                                const float* __restrict__ aW2,
                                                const float* __restrict__ ab2,
                                                float* __restrict__ gate, int N) {
    int w = (blockIdx.x * blockDim.x + threadIdx.x) >> 6;
    if (w >= N) return;
    int lane = threadIdx.x & 63;
    const float* ph = hid + (size_t)w * 128;
    float a = ph[lane] * aW2[lane] + ph[lane + 64] * aW2[lane + 64];
    #pragma unroll
    for (int s = 32; s; s >>= 1) a += __shfl_xor(a, s);
    if (lane == 0) gate[w] = a + ab2[0];
}

__global__ __launch_bounds__(128) void attn_pool(const float* __restrict__ x,
                                                 const float* __restrict__ gate,
                                                 const int* __restrict__ batch,
                                                 int N, float* __restrict__ out) {
    const int b   = blockIdx.x;
    const int tid = threadIdx.x;
    int lo, hi;
    { int l = 0, r = N; while (l < r) { int mid = (l + r) >> 1; if (batch[mid] < b) l = mid + 1; else r = mid; } lo = l; }
    { int l = lo, r = N; while (l < r) { int mid = (l + r) >> 1; if (batch[mid] < b + 1) l = mid + 1; else r = mid; } hi = l; }
    if (lo >= hi) { out[b * 128 + tid] = 0.f; return; }

    __shared__ float red[128];
    float mx = -INFINITY;
    for (int n = lo + tid; n < hi; n += 128) mx = fmaxf(mx, gate[n]);
    red[tid] = mx; __syncthreads();
    for (int s = 64; s; s >>= 1) { if (tid < s) red[tid] = fmaxf(red[tid], red[tid + s]); __syncthreads(); }
    mx = red[0]; __syncthreads();

    float zs = 0.f;
    for (int n = lo + tid; n < hi; n += 128) zs += __expf(gate[n] - mx);
    red[tid] = zs; __syncthreads();
    for (int s = 64; s; s >>= 1) { if (tid < s) red[tid] += red[tid + s]; __syncthreads(); }
    zs = red[0];

    float acc = 0.f;
    for (int n = lo; n < hi; ++n)
        acc += __expf(gate[n] - mx) * x[(size_t)n * 128 + tid];
    out[b * 128 + tid] = acc / (zs + 1e-16f);
}

// ---------------------------------------------------------------------------
extern "C" void kernel_launch(void* const* d_in, const int* in_sizes, int n_in,
                              void* d_out, int out_size, void* d_ws, size_t ws_size,
                              hipStream_t stream) {
    const float* x0  = (const float*)d_in[0];
    const int* edge  = (const int*)d_in[1];
    const int* batch = (const int*)d_in[2];
    const int N = in_sizes[2];
    const int E = in_sizes[1] / 2;
    const int Etot = E + N;
    const int dims[4] = {960, 512, 256, 128};

    const float* Wl[3]   = {(const float*)d_in[3],  (const float*)d_in[10], (const float*)d_in[17]};
    const float* Wr[3]   = {(const float*)d_in[4],  (const float*)d_in[11], (const float*)d_in[18]};
    const float* attp[3] = {(const float*)d_in[5],  (const float*)d_in[12], (const float*)d_in[19]};
    const float* bi[3]   = {(const float*)d_in[6],  (const float*)d_in[13], (const float*)d_in[20]};
    const float* gw[3]   = {(const float*)d_in[7],  (const float*)d_in[14], (const float*)d_in[21]};
    const float* gb[3]   = {(const float*)d_in[8],  (const float*)d_in[15], (const float*)d_in[22]};
    const float* gm[3]   = {(const float*)d_in[9],  (const float*)d_in[16], (const float*)d_in[23]};
    const float* aW1 = (const float*)d_in[24];
    const float* ab1 = (const float*)d_in[25];
    const float* aW2 = (const float*)d_in[26];
    const float* ab2 = (const float*)d_in[27];

    size_t off = 0;
    auto alloc = [&](size_t bytes) -> char* {
        char* p = (char*)d_ws + off;
        off += (bytes + 255) & ~(size_t)255;
        return p;
    };
    float* bufA      = (float*)alloc((size_t)N * 512 * 4);
    float* bufB      = (float*)alloc((size_t)N * 512 * 4);
    float* bufC      = (float*)alloc((size_t)N * 512 * 4);
    int*   deg       = (int*)alloc((size_t)N * 4);
    int*   row_start = (int*)alloc((size_t)(N + 1) * 4);
    int*   cursor    = (int*)alloc((size_t)N * 4);
    int*   src_perm  = (int*)alloc((size_t)Etot * 4);
    float* s1        = (float*)alloc(512 * 4);
    float* s2        = (float*)alloc(512 * 4);
    float* alB       = (float*)alloc(512 * 4);
    float* beB       = (float*)alloc(512 * 4);
    float* gateB     = (float*)alloc((size_t)N * 4);
    // split/transposed weights (bf16)
    __bf16* wlh[3]; __bf16* wll[3]; __bf16* wrh[3]; __bf16* wrl[3];
    for (int l = 0; l < 3; ++l) {
        size_t sz = (size_t)dims[l] * dims[l + 1] * 2;
        wlh[l] = (__bf16*)alloc(sz); wll[l] = (__bf16*)alloc(sz);
        wrh[l] = (__bf16*)alloc(sz); wrl[l] = (__bf16*)alloc(sz);
    }
    __bf16* awh = (__bf16*)alloc(128 * 128 * 2);
    __bf16* awl = (__bf16*)alloc(128 * 128 * 2);
    (void)ws_size; (void)n_in; (void)out_size;

    // ---- one-time weight transpose + split ----
    for (int l = 0; l < 3; ++l) {
        int tot = dims[l] * dims[l + 1];
        conv_w<<<(tot + 255) / 256, 256, 0, stream>>>(Wl[l], wlh[l], wll[l], dims[l], dims[l + 1]);
        conv_w<<<(tot + 255) / 256, 256, 0, stream>>>(Wr[l], wrh[l], wrl[l], dims[l], dims[l + 1]);
    }
    conv_w<<<(128 * 128 + 255) / 256, 256, 0, stream>>>(aW1, awh, awl, 128, 128);

    // ---- CSR by dst ----
    hipMemsetAsync(deg, 0, (size_t)N * sizeof(int), stream);
    csr_count<<<(Etot + 255) / 256, 256, 0, stream>>>(edge + E, E, Etot, deg);
    scan_deg<<<1, 1024, 0, stream>>>(deg, row_start, N);
    hipMemcpyAsync(cursor, row_start, (size_t)N * sizeof(int),
                   hipMemcpyDeviceToDevice, stream);
    csr_fill<<<(Etot + 255) / 256, 256, 0, stream>>>(edge, edge + E, E, Etot,
                                                     cursor, src_perm);

    for (int l = 0; l < 3; ++l) {
        const int K = dims[l], HC = dims[l + 1];
        const float* xin = (l == 0) ? x0 : bufC;
        dim3 ggrid(HC / 128, N / 128);
        mfma_gemm<false, false><<<ggrid, 256, 0, stream>>>(xin, wlh[l], wll[l], nullptr, bufA, N, K, HC);
        mfma_gemm<false, false><<<ggrid, 256, 0, stream>>>(xin, wrh[l], wrl[l], nullptr, bufB, N, K, HC);

        const int agrid = (N + 3) / 4;
        if (l == 0)      gat_agg<7><<<agrid, 256, 0, stream>>>(bufA, bufB, attp[l], bi[l], row_start, src_perm, N, bufC);
        else if (l == 1) gat_agg<6><<<agrid, 256, 0, stream>>>(bufA, bufB, attp[l], bi[l], row_start, src_perm, N, bufC);
        else             gat_agg<5><<<agrid, 256, 0, stream>>>(bufA, bufB, attp[l], bi[l], row_start, src_perm, N, bufC);

        hipMemsetAsync(s1, 0, HC * sizeof(float), stream);
        hipMemsetAsync(s2, 0, HC * sizeof(float), stream);
        colstats<<<dim3(HC / 64, N / 128), 64, 0, stream>>>(bufC, HC, s1, s2);
        gn_finalize<<<(HC + 63) / 64, 64, 0, stream>>>(s1, s2, gw[l], gb[l], gm[l], HC, 1.0f / N, alB, beB);
        norm_relu<<<(N * HC + 255) / 256, 256, 0, stream>>>(bufC, alB, beB, N * HC, HC - 1);
    }

    // ---- attentional pooling ----
    mfma_gemm<true, true><<<dim3(1, N / 128), 256, 0, stream>>>(bufC, awh, awl, ab1, bufA, N, 128, 128);
    gate_dot<<<(N * 64 + 255) / 256, 256, 0, stream>>>(bufA, aW2, ab2, gateB, N);
    attn_pool<<<64, 128, 0, stream>>>(bufC, gateB, batch, N, (float*)d_out);
}

// Round 4
// 590.669 us; speedup vs baseline: 3.7250x; 1.3904x over previous
//
#include <hip/hip_runtime.h>
#include <cstdint>
#include <cstddef>
#include <math.h>

// ---------------------------------------------------------------------------
// GATv2 x3 + GraphNorm + ReLU + attentional pooling.
// Round 4:
//  - xl/xr stored as fp16 (GEMM epilogue converts); gat_agg gathers each
//    edge row ONCE into registers (8-edge chunks), online softmax per head.
//  - Wl/Wr fused into one GEMM per layer (stacked [2HC][K] weights).
// ---------------------------------------------------------------------------

typedef __bf16    bf16x8 __attribute__((ext_vector_type(8)));
typedef float     f32x4  __attribute__((ext_vector_type(4)));
typedef _Float16  h16x8  __attribute__((ext_vector_type(8)));
typedef _Float16  h16x4  __attribute__((ext_vector_type(4)));
typedef _Float16  h16x2  __attribute__((ext_vector_type(2)));

template<int R> struct HV;
template<> struct HV<8> { using T = h16x8; };
template<> struct HV<4> { using T = h16x4; };
template<> struct HV<2> { using T = h16x2; };

// ---------------------------------------------------------------------------
// Weight conversion: W [K][N] fp32 -> Wt_hi/lo [N][K] bf16 (transposed, split)
// ---------------------------------------------------------------------------
__global__ void conv_w(const float* __restrict__ W, __bf16* __restrict__ Whi,
                       __bf16* __restrict__ Wlo, int K, int N) {
    int t = blockIdx.x * blockDim.x + threadIdx.x;
    if (t >= K * N) return;
    int k = t / N, n = t - k * N;
    float v = W[t];
    __bf16 h = (__bf16)v;
    Whi[(size_t)n * K + k] = h;
    Wlo[(size_t)n * K + k] = (__bf16)(v - (float)h);
}

// ---------------------------------------------------------------------------
// MFMA GEMM: C[M,N] = A[M,K](fp32) @ Bt[N,K](bf16 hi/lo, pre-transposed)
// bf16x3 split: A@B ~= Ahi@Bhi + Ahi@Blo + Alo@Bhi  (fp32-accurate)
// 128x128 tile, 4 waves (2x2), each wave 64x64 = 4x4 frags of 16x16x32.
// ---------------------------------------------------------------------------
template<bool BIAS, bool RELU, typename OutT>
__global__ __launch_bounds__(256) void mfma_gemm(
        const float* __restrict__ A,
        const __bf16* __restrict__ Bthi, const __bf16* __restrict__ Btlo,
        const float* __restrict__ bias, OutT* __restrict__ C,
        int M, int K, int N) {
    __shared__ __attribute__((aligned(16))) __bf16 sAh[128 * 32];
    __shared__ __attribute__((aligned(16))) __bf16 sAl[128 * 32];
    __shared__ __attribute__((aligned(16))) __bf16 sBh[128 * 32];
    __shared__ __attribute__((aligned(16))) __bf16 sBl[128 * 32];

    const int tid  = threadIdx.x;
    const int row0 = blockIdx.y * 128;
    const int col0 = blockIdx.x * 128;
    const int lane = tid & 63;
    const int w    = tid >> 6;
    const int wm   = w >> 1, wn = w & 1;
    const int lr   = lane & 15, lg = lane >> 4;
    const int sr   = tid >> 2;            // staging row 0..63
    const int sc   = (tid & 3) * 8;       // staging k-chunk {0,8,16,24}

    f32x4 acc[4][4] = {};

    for (int k0 = 0; k0 < K; k0 += 32) {
        #pragma unroll
        for (int half = 0; half < 2; ++half) {
            const int rr = sr + half * 64;
            const float* src = A + (size_t)(row0 + rr) * K + k0 + sc;
            float4 u0 = *(const float4*)src;
            float4 u1 = *(const float4*)(src + 4);
            float uu[8] = {u0.x, u0.y, u0.z, u0.w, u1.x, u1.y, u1.z, u1.w};
            bf16x8 h, lo;
            #pragma unroll
            for (int j = 0; j < 8; ++j) {
                __bf16 hh = (__bf16)uu[j];
                h[j]  = hh;
                lo[j] = (__bf16)(uu[j] - (float)hh);
            }
            *(bf16x8*)&sAh[rr * 32 + sc] = h;
            *(bf16x8*)&sAl[rr * 32 + sc] = lo;
            *(bf16x8*)&sBh[rr * 32 + sc] =
                *(const bf16x8*)(Bthi + (size_t)(col0 + rr) * K + k0 + sc);
            *(bf16x8*)&sBl[rr * 32 + sc] =
                *(const bf16x8*)(Btlo + (size_t)(col0 + rr) * K + k0 + sc);
        }
        __syncthreads();

        bf16x8 ah[4], al[4], bh[4], bl[4];
        #pragma unroll
        for (int i = 0; i < 4; ++i) {
            const int ar = (wm * 64 + i * 16 + lr) * 32 + lg * 8;
            const int bc = (wn * 64 + i * 16 + lr) * 32 + lg * 8;
            ah[i] = *(const bf16x8*)&sAh[ar];
            al[i] = *(const bf16x8*)&sAl[ar];
            bh[i] = *(const bf16x8*)&sBh[bc];
            bl[i] = *(const bf16x8*)&sBl[bc];
        }
        #pragma unroll
        for (int i = 0; i < 4; ++i)
            #pragma unroll
            for (int j = 0; j < 4; ++j) {
                acc[i][j] = __builtin_amdgcn_mfma_f32_16x16x32_bf16(ah[i], bh[j], acc[i][j], 0, 0, 0);
                acc[i][j] = __builtin_amdgcn_mfma_f32_16x16x32_bf16(ah[i], bl[j], acc[i][j], 0, 0, 0);
                acc[i][j] = __builtin_amdgcn_mfma_f32_16x16x32_bf16(al[i], bh[j], acc[i][j], 0, 0, 0);
            }
        __syncthreads();
    }

    #pragma unroll
    for (int i = 0; i < 4; ++i) {
        const int rowb = row0 + wm * 64 + i * 16 + lg * 4;
        #pragma unroll
        for (int j = 0; j < 4; ++j) {
            const int col = col0 + wn * 64 + j * 16 + lr;
            const float bv = BIAS ? bias[col] : 0.f;
            #pragma unroll
            for (int q = 0; q < 4; ++q) {
                float v = acc[i][j][q] + bv;
                if (RELU) v = fmaxf(v, 0.f);
                C[(size_t)(rowb + q) * N + col] = (OutT)v;
            }
        }
    }
}

// ---------------------------------------------------------------------------
// CSR build (once per call; edge_index is layer-invariant).
// ---------------------------------------------------------------------------
__global__ void csr_count(const int* __restrict__ edst, int E, int Etot,
                          int* __restrict__ deg) {
    int e = blockIdx.x * blockDim.x + threadIdx.x;
    if (e >= Etot) return;
    int d = (e < E) ? edst[e] : e - E;
    atomicAdd(&deg[d], 1);
}

__global__ __launch_bounds__(1024) void scan_deg(const int* __restrict__ deg,
                                                 int* __restrict__ row_start, int N) {
    __shared__ int sh[1024];
    const int tid = threadIdx.x;
    int carry = 0;
    for (int base = 0; base < N; base += 1024) {
        int i = base + tid;
        sh[tid] = (i < N) ? deg[i] : 0;
        __syncthreads();
        #pragma unroll
        for (int off = 1; off < 1024; off <<= 1) {
            int t = (tid >= off) ? sh[tid - off] : 0;
            __syncthreads();
            sh[tid] += t;
            __syncthreads();
        }
        if (i < N) row_start[i + 1] = carry + sh[tid];
        carry += sh[1023];
        __syncthreads();
    }
    if (tid == 0) row_start[0] = 0;
}

__global__ void csr_fill(const int* __restrict__ esrc, const int* __restrict__ edst,
                         int E, int Etot, int* __restrict__ cursor,
                         int* __restrict__ src_perm) {
    int e = blockIdx.x * blockDim.x + threadIdx.x;
    if (e >= Etot) return;
    int s, d;
    if (e < E) { s = esrc[e]; d = edst[e]; }
    else       { s = d = e - E; }
    int pos = atomicAdd(&cursor[d], 1);
    src_perm[pos] = s;
}

// ---------------------------------------------------------------------------
// Fused GATv2 edge phase, gather form, fp16 features, single gather per edge.
// One wave per dst node. xlr holds [xl | xr] per row (stride 2*HC).
// Lane owns R contiguous channels (all in head lane>>4); logit reduce is a
// 4-step shfl_xor within the 16-lane head group; online softmax per lane.
// ---------------------------------------------------------------------------
template<int LOG2C>
__global__ __launch_bounds__(256) void gat_agg(
        const _Float16* __restrict__ xlr,
        const float* __restrict__ att, const float* __restrict__ bias,
        const int* __restrict__ row_start, const int* __restrict__ src_perm,
        int N, float* __restrict__ out) {
    constexpr int HC  = 4 << LOG2C;     // 512 / 256 / 128
    constexpr int R   = HC / 64;        // 8 / 4 / 2 channels per lane
    constexpr int STR = 2 * HC;         // xlr row stride
    constexpr int CAP = 8;              // edges per register chunk
    using hvec = typename HV<R>::T;

    const int widx = threadIdx.x >> 6;
    const int lane = threadIdx.x & 63;
    const int dst  = blockIdx.x * 4 + widx;
    if (dst >= N) return;

    const int base = lane * R;
    float xrv[R], attv[R], acc[R];
    {
        hvec xv = *(const hvec*)&xlr[(size_t)dst * STR + HC + base];
        #pragma unroll
        for (int it = 0; it < R; ++it) {
            xrv[it]  = (float)xv[it];
            attv[it] = att[base + it];
            acc[it]  = 0.f;
        }
    }

    float m = -INFINITY, z = 0.f;
    const int start = row_start[dst], end = row_start[dst + 1];

    for (int cs = start; cs < end; cs += CAP) {
        const int cnt = min(CAP, end - cs);   // wave-uniform
        hvec  rows[CAP];
        float lg[CAP];
        float cmax = -INFINITY;
        #pragma unroll
        for (int k = 0; k < CAP; ++k) {
            if (k < cnt) {
                int src = __builtin_amdgcn_readfirstlane(src_perm[cs + k]);
                rows[k] = *(const hvec*)&xlr[(size_t)src * STR + base];
                float a = 0.f;
                #pragma unroll
                for (int it = 0; it < R; ++it) {
                    float v = (float)rows[k][it] + xrv[it];
                    v = v > 0.f ? v : 0.2f * v;       // leaky_relu(0.2)
                    a += v * attv[it];
                }
                #pragma unroll
                for (int s = 1; s < 16; s <<= 1) a += __shfl_xor(a, s);
                lg[k] = a;
                cmax = fmaxf(cmax, a);
            }
        }
        // online softmax merge
        float nm = fmaxf(m, cmax);
        float sc = __expf(m - nm);
        z *= sc;
        #pragma unroll
        for (int it = 0; it < R; ++it) acc[it] *= sc;
        m = nm;
        #pragma unroll
        for (int k = 0; k < CAP; ++k) {
            if (k < cnt) {
                float p = __expf(lg[k] - m);
                z += p;
                #pragma unroll
                for (int it = 0; it < R; ++it) acc[it] += p * (float)rows[k][it];
            }
        }
    }

    const float inv = 1.f / (z + 1e-16f);
    float ov[R];
    #pragma unroll
    for (int it = 0; it < R; ++it) ov[it] = acc[it] * inv + bias[base + it];
    float* po = out + (size_t)dst * HC + base;
    if constexpr (R == 8) {
        *(float4*)po       = make_float4(ov[0], ov[1], ov[2], ov[3]);
        *(float4*)(po + 4) = make_float4(ov[4], ov[5], ov[6], ov[7]);
    } else if constexpr (R == 4) {
        *(float4*)po = make_float4(ov[0], ov[1], ov[2], ov[3]);
    } else {
        *(float2*)po = make_float2(ov[0], ov[1]);
    }
}

// ---------------------------------------------------------------------------
// GraphNorm + ReLU
// ---------------------------------------------------------------------------
__global__ __launch_bounds__(64) void colstats(const float* __restrict__ x, int HC,
                                               float* __restrict__ s1, float* __restrict__ s2) {
    int c  = blockIdx.x * 64 + threadIdx.x;
    int r0 = blockIdx.y * 128;
    float a = 0.f, b = 0.f;
    for (int r = r0; r < r0 + 128; ++r) {
        float v = x[(size_t)r * HC + c];
        a += v; b += v * v;
    }
    atomicAdd(&s1[c], a);
    atomicAdd(&s2[c], b);
}

__global__ void gn_finalize(const float* __restrict__ s1, const float* __restrict__ s2,
                            const float* __restrict__ w, const float* __restrict__ b,
                            const float* __restrict__ ms, int HC, float invN,
                            float* __restrict__ alpha, float* __restrict__ beta) {
    int c = blockIdx.x * blockDim.x + threadIdx.x;
    if (c >= HC) return;
    float mean = s1[c] * invN;
    float ex2  = s2[c] * invN;
    float a    = ms[c] * mean;
    float var  = ex2 - 2.f * a * mean + a * a;
    float al   = w[c] * rsqrtf(var + 1e-5f);
    alpha[c] = al;
    beta[c]  = b[c] - a * al;
}

__global__ void norm_relu(float* __restrict__ x, const float* __restrict__ alpha,
                          const float* __restrict__ beta, int total, int mask) {
    int t = blockIdx.x * blockDim.x + threadIdx.x;
    if (t >= total) return;
    int c = t & mask;
    x[t] = fmaxf(alpha[c] * x[t] + beta[c], 0.f);
}

// ---------------------------------------------------------------------------
__global__ __launch_bounds__(256) void gate_dot(const float* __restrict__ hid,
                                                const float* __restrict__ aW2,
                                                const float* __restrict__ ab2,
                                                float* __restrict__ gate, int N) {
    int w = (blockIdx.x * blockDim.x + threadIdx.x) >> 6;
    if (w >= N) return;
    int lane = threadIdx.x & 63;
    const float* ph = hid + (size_t)w * 128;
    float a = ph[lane] * aW2[lane] + ph[lane + 64] * aW2[lane + 64];
    #pragma unroll
    for (int s = 32; s; s >>= 1) a += __shfl_xor(a, s);
    if (lane == 0) gate[w] = a + ab2[0];
}

__global__ __launch_bounds__(128) void attn_pool(const float* __restrict__ x,
                                                 const float* __restrict__ gate,
                                                 const int* __restrict__ batch,
                                                 int N, float* __restrict__ out) {
    const int b   = blockIdx.x;
    const int tid = threadIdx.x;
    int lo, hi;
    { int l = 0, r = N; while (l < r) { int mid = (l + r) >> 1; if (batch[mid] < b) l = mid + 1; else r = mid; } lo = l; }
    { int l = lo, r = N; while (l < r) { int mid = (l + r) >> 1; if (batch[mid] < b + 1) l = mid + 1; else r = mid; } hi = l; }
    if (lo >= hi) { out[b * 128 + tid] = 0.f; return; }

    __shared__ float red[128];
    float mx = -INFINITY;
    for (int n = lo + tid; n < hi; n += 128) mx = fmaxf(mx, gate[n]);
    red[tid] = mx; __syncthreads();
    for (int s = 64; s; s >>= 1) { if (tid < s) red[tid] = fmaxf(red[tid], red[tid + s]); __syncthreads(); }
    mx = red[0]; __syncthreads();

    float zs = 0.f;
    for (int n = lo + tid; n < hi; n += 128) zs += __expf(gate[n] - mx);
    red[tid] = zs; __syncthreads();
    for (int s = 64; s; s >>= 1) { if (tid < s) red[tid] += red[tid + s]; __syncthreads(); }
    zs = red[0];

    float acc = 0.f;
    for (int n = lo; n < hi; ++n)
        acc += __expf(gate[n] - mx) * x[(size_t)n * 128 + tid];
    out[b * 128 + tid] = acc / (zs + 1e-16f);
}

// ---------------------------------------------------------------------------
extern "C" void kernel_launch(void* const* d_in, const int* in_sizes, int n_in,
                              void* d_out, int out_size, void* d_ws, size_t ws_size,
                              hipStream_t stream) {
    const float* x0  = (const float*)d_in[0];
    const int* edge  = (const int*)d_in[1];
    const int* batch = (const int*)d_in[2];
    const int N = in_sizes[2];
    const int E = in_sizes[1] / 2;
    const int Etot = E + N;
    const int dims[4] = {960, 512, 256, 128};

    const float* Wl[3]   = {(const float*)d_in[3],  (const float*)d_in[10], (const float*)d_in[17]};
    const float* Wr[3]   = {(const float*)d_in[4],  (const float*)d_in[11], (const float*)d_in[18]};
    const float* attp[3] = {(const float*)d_in[5],  (const float*)d_in[12], (const float*)d_in[19]};
    const float* bi[3]   = {(const float*)d_in[6],  (const float*)d_in[13], (const float*)d_in[20]};
    const float* gw[3]   = {(const float*)d_in[7],  (const float*)d_in[14], (const float*)d_in[21]};
    const float* gb[3]   = {(const float*)d_in[8],  (const float*)d_in[15], (const float*)d_in[22]};
    const float* gm[3]   = {(const float*)d_in[9],  (const float*)d_in[16], (const float*)d_in[23]};
    const float* aW1 = (const float*)d_in[24];
    const float* ab1 = (const float*)d_in[25];
    const float* aW2 = (const float*)d_in[26];
    const float* ab2 = (const float*)d_in[27];

    size_t off = 0;
    auto alloc = [&](size_t bytes) -> char* {
        char* p = (char*)d_ws + off;
        off += (bytes + 255) & ~(size_t)255;
        return p;
    };
    _Float16* xlr     = (_Float16*)alloc((size_t)N * 1024 * 2);  // [xl|xr] fp16
    float*   bufC     = (float*)alloc((size_t)N * 512 * 4);      // x / layer out
    int*     deg      = (int*)alloc((size_t)N * 4);
    int*     row_start= (int*)alloc((size_t)(N + 1) * 4);
    int*     cursor   = (int*)alloc((size_t)N * 4);
    int*     src_perm = (int*)alloc((size_t)Etot * 4);
    float*   s1       = (float*)alloc(512 * 4);
    float*   s2       = (float*)alloc(512 * 4);
    float*   alB      = (float*)alloc(512 * 4);
    float*   beB      = (float*)alloc(512 * 4);
    float*   gateB    = (float*)alloc((size_t)N * 4);
    // stacked split/transposed weights: [Wl^T ; Wr^T] -> [2HC][K] bf16
    __bf16* wh[3]; __bf16* wl[3];
    for (int l = 0; l < 3; ++l) {
        size_t sz = (size_t)dims[l] * (2 * dims[l + 1]) * 2;
        wh[l] = (__bf16*)alloc(sz); wl[l] = (__bf16*)alloc(sz);
    }
    __bf16* awh = (__bf16*)alloc(128 * 128 * 2);
    __bf16* awl = (__bf16*)alloc(128 * 128 * 2);
    float* poolhid = (float*)xlr;    // reuse: xlr dead at pooling time (8MB <= 32MB)
    (void)ws_size; (void)n_in; (void)out_size;

    // ---- one-time weight transpose + split (Wl into rows [0,HC), Wr into [HC,2HC)) ----
    for (int l = 0; l < 3; ++l) {
        int K = dims[l], HC = dims[l + 1];
        int tot = K * HC;
        conv_w<<<(tot + 255) / 256, 256, 0, stream>>>(Wl[l], wh[l], wl[l], K, HC);
        conv_w<<<(tot + 255) / 256, 256, 0, stream>>>(Wr[l], wh[l] + (size_t)HC * K, wl[l] + (size_t)HC * K, K, HC);
    }
    conv_w<<<(128 * 128 + 255) / 256, 256, 0, stream>>>(aW1, awh, awl, 128, 128);

    // ---- CSR by dst ----
    hipMemsetAsync(deg, 0, (size_t)N * sizeof(int), stream);
    csr_count<<<(Etot + 255) / 256, 256, 0, stream>>>(edge + E, E, Etot, deg);
    scan_deg<<<1, 1024, 0, stream>>>(deg, row_start, N);
    hipMemcpyAsync(cursor, row_start, (size_t)N * sizeof(int),
                   hipMemcpyDeviceToDevice, stream);
    csr_fill<<<(Etot + 255) / 256, 256, 0, stream>>>(edge, edge + E, E, Etot,
                                                     cursor, src_perm);

    for (int l = 0; l < 3; ++l) {
        const int K = dims[l], HC = dims[l + 1];
        const float* xin = (l == 0) ? x0 : bufC;
        // fused xl|xr GEMM: C[N][2HC] fp16
        dim3 ggrid((2 * HC) / 128, N / 128);
        mfma_gemm<false, false, _Float16><<<ggrid, 256, 0, stream>>>(
            xin, wh[l], wl[l], nullptr, xlr, N, K, 2 * HC);

        const int agrid = (N + 3) / 4;
        if (l == 0)      gat_agg<7><<<agrid, 256, 0, stream>>>(xlr, attp[l], bi[l], row_start, src_perm, N, bufC);
        else if (l == 1) gat_agg<6><<<agrid, 256, 0, stream>>>(xlr, attp[l], bi[l], row_start, src_perm, N, bufC);
        else             gat_agg<5><<<agrid, 256, 0, stream>>>(xlr, attp[l], bi[l], row_start, src_perm, N, bufC);

        hipMemsetAsync(s1, 0, HC * sizeof(float), stream);
        hipMemsetAsync(s2, 0, HC * sizeof(float), stream);
        colstats<<<dim3(HC / 64, N / 128), 64, 0, stream>>>(bufC, HC, s1, s2);
        gn_finalize<<<(HC + 63) / 64, 64, 0, stream>>>(s1, s2, gw[l], gb[l], gm[l], HC, 1.0f / N, alB, beB);
        norm_relu<<<(N * HC + 255) / 256, 256, 0, stream>>>(bufC, alB, beB, N * HC, HC - 1);
    }

    // ---- attentional pooling ----
    mfma_gemm<true, true, float><<<dim3(1, N / 128), 256, 0, stream>>>(
        bufC, awh, awl, ab1, poolhid, N, 128, 128);
    gate_dot<<<(N * 64 + 255) / 256, 256, 0, stream>>>(poolhid, aW2, ab2, gateB, N);
    attn_pool<<<64, 128, 0, stream>>>(bufC, gateB, batch, N, (float*)d_out);
}

// Round 5
// 492.224 us; speedup vs baseline: 4.4700x; 1.2000x over previous
//
#include <hip/hip_runtime.h>
#include <cstdint>
#include <cstddef>
#include <math.h>

// ---------------------------------------------------------------------------
// GATv2 x3 + GraphNorm + ReLU + attentional pooling.
// Round 5:
//  - GEMM: fp16x2 scheme (A split fp16 hi/lo -> 2 MFMAs; B single fp16).
//  - XCD-chunked block swizzle (all col-tiles of a row-tile on one XCD L2).
//  - GraphNorm+ReLU fused into next GEMM's A staging / attn_pool.
//  - fewer dispatches: fused conv, scan emits cursor, single stats memset.
// ---------------------------------------------------------------------------

typedef _Float16  h16x8  __attribute__((ext_vector_type(8)));
typedef _Float16  h16x4  __attribute__((ext_vector_type(4)));
typedef _Float16  h16x2  __attribute__((ext_vector_type(2)));
typedef float     f32x4  __attribute__((ext_vector_type(4)));

template<int R> struct HV;
template<> struct HV<8> { using T = h16x8; };
template<> struct HV<4> { using T = h16x4; };
template<> struct HV<2> { using T = h16x2; };

// ---------------------------------------------------------------------------
// Weight conversion: Wl/Wr [K][HC] fp32 -> Wt [2HC][K] fp16 (transposed,
// stacked). Wr may be null (single matrix).
// ---------------------------------------------------------------------------
__global__ void conv_wf16(const float* __restrict__ Wl, const float* __restrict__ Wr,
                          _Float16* __restrict__ Wt, int K, int HC) {
    int t = blockIdx.x * blockDim.x + threadIdx.x;
    if (t >= K * HC) return;
    int k = t / HC, n = t - k * HC;
    Wt[(size_t)n * K + k] = (_Float16)Wl[t];
    if (Wr) Wt[(size_t)(HC + n) * K + k] = (_Float16)Wr[t];
}

// ---------------------------------------------------------------------------
// MFMA GEMM: C[M,N] = f(A)[M,K](fp32) @ Bt[N,K](fp16, pre-transposed)
// fp16x2: A@B ~= Ahi@B + Alo@B with Ahi/Alo fp16 split of (optionally
// graphnorm+relu'd) A. 128x128 tile, 4 waves (2x2), 16x16x32 f16 MFMA.
// XCD-chunked bijective block swizzle for L2 locality.
// ---------------------------------------------------------------------------
template<bool NORM, bool BIAS, bool RELU, typename OutT>
__global__ __launch_bounds__(256) void mfma_gemm(
        const float* __restrict__ A, const _Float16* __restrict__ Bt,
        const float* __restrict__ alp, const float* __restrict__ bet,
        const float* __restrict__ bias, OutT* __restrict__ C,
        int M, int K, int N) {
    __shared__ __attribute__((aligned(16))) _Float16 sAh[128 * 32];
    __shared__ __attribute__((aligned(16))) _Float16 sAl[128 * 32];
    __shared__ __attribute__((aligned(16))) _Float16 sB [128 * 32];

    // ---- bijective XCD-chunked swizzle (m204) ----
    const int gx  = gridDim.x;
    const int nwg = gx * gridDim.y;
    const int id  = blockIdx.y * gx + blockIdx.x;
    const int q   = nwg >> 3, r = nwg & 7;
    const int xcd = id & 7, sub = id >> 3;
    const int nid = (xcd < r) ? (xcd * (q + 1) + sub)
                              : (r * (q + 1) + (xcd - r) * q + sub);
    const int row0 = (nid / gx) * 128;
    const int col0 = (nid % gx) * 128;

    const int tid  = threadIdx.x;
    const int lane = tid & 63;
    const int w    = tid >> 6;
    const int wm   = w >> 1, wn = w & 1;
    const int lr   = lane & 15, lg = lane >> 4;
    const int sr   = tid >> 2;            // staging row 0..63
    const int sc   = (tid & 3) * 8;       // staging k-chunk {0,8,16,24}

    f32x4 acc[4][4] = {};

    for (int k0 = 0; k0 < K; k0 += 32) {
        float4 aav0, aav1, bbv0, bbv1;
        if (NORM) {
            aav0 = *(const float4*)(alp + k0 + sc);
            aav1 = *(const float4*)(alp + k0 + sc + 4);
            bbv0 = *(const float4*)(bet + k0 + sc);
            bbv1 = *(const float4*)(bet + k0 + sc + 4);
        }
        #pragma unroll
        for (int half = 0; half < 2; ++half) {
            const int rr = sr + half * 64;
            const float* src = A + (size_t)(row0 + rr) * K + k0 + sc;
            float4 u0 = *(const float4*)src;
            float4 u1 = *(const float4*)(src + 4);
            float uu[8] = {u0.x, u0.y, u0.z, u0.w, u1.x, u1.y, u1.z, u1.w};
            if (NORM) {
                float aa[8] = {aav0.x, aav0.y, aav0.z, aav0.w, aav1.x, aav1.y, aav1.z, aav1.w};
                float bb[8] = {bbv0.x, bbv0.y, bbv0.z, bbv0.w, bbv1.x, bbv1.y, bbv1.z, bbv1.w};
                #pragma unroll
                for (int j = 0; j < 8; ++j)
                    uu[j] = fmaxf(aa[j] * uu[j] + bb[j], 0.f);
            }
            h16x8 h, lo;
            #pragma unroll
            for (int j = 0; j < 8; ++j) {
                _Float16 hh = (_Float16)uu[j];
                h[j]  = hh;
                lo[j] = (_Float16)(uu[j] - (float)hh);
            }
            *(h16x8*)&sAh[rr * 32 + sc] = h;
            *(h16x8*)&sAl[rr * 32 + sc] = lo;
            *(h16x8*)&sB [rr * 32 + sc] =
                *(const h16x8*)(Bt + (size_t)(col0 + rr) * K + k0 + sc);
        }
        __syncthreads();

        h16x8 ah[4], al[4], bf[4];
        #pragma unroll
        for (int i = 0; i < 4; ++i) {
            const int ar = (wm * 64 + i * 16 + lr) * 32 + lg * 8;
            const int bc = (wn * 64 + i * 16 + lr) * 32 + lg * 8;
            ah[i] = *(const h16x8*)&sAh[ar];
            al[i] = *(const h16x8*)&sAl[ar];
            bf[i] = *(const h16x8*)&sB [bc];
        }
        #pragma unroll
        for (int i = 0; i < 4; ++i)
            #pragma unroll
            for (int j = 0; j < 4; ++j) {
                acc[i][j] = __builtin_amdgcn_mfma_f32_16x16x32_f16(ah[i], bf[j], acc[i][j], 0, 0, 0);
                acc[i][j] = __builtin_amdgcn_mfma_f32_16x16x32_f16(al[i], bf[j], acc[i][j], 0, 0, 0);
            }
        __syncthreads();
    }

    #pragma unroll
    for (int i = 0; i < 4; ++i) {
        const int rowb = row0 + wm * 64 + i * 16 + lg * 4;
        #pragma unroll
        for (int j = 0; j < 4; ++j) {
            const int col = col0 + wn * 64 + j * 16 + lr;
            const float bv = BIAS ? bias[col] : 0.f;
            #pragma unroll
            for (int qq = 0; qq < 4; ++qq) {
                float v = acc[i][j][qq] + bv;
                if (RELU) v = fmaxf(v, 0.f);
                C[(size_t)(rowb + qq) * N + col] = (OutT)v;
            }
        }
    }
}

// ---------------------------------------------------------------------------
// CSR build (once per call; edge_index is layer-invariant).
// ---------------------------------------------------------------------------
__global__ void csr_count(const int* __restrict__ edst, int E, int Etot,
                          int* __restrict__ deg) {
    int e = blockIdx.x * blockDim.x + threadIdx.x;
    if (e >= Etot) return;
    int d = (e < E) ? edst[e] : e - E;
    atomicAdd(&deg[d], 1);
}

// single-block scan: 16 items/thread serial + 1024-wide Hillis-Steele.
// writes row_start[0..N] AND cursor[0..N-1] (= segment starts).
__global__ __launch_bounds__(1024) void scan_deg(const int* __restrict__ deg,
                                                 int* __restrict__ row_start,
                                                 int* __restrict__ cursor, int N) {
    __shared__ int part[1024];
    const int tid = threadIdx.x;
    const int base = tid * 16;
    int loc[16];
    int s = 0;
    #pragma unroll
    for (int j = 0; j < 16; ++j) {
        int i = base + j;
        s += (i < N) ? deg[i] : 0;
        loc[j] = s;
    }
    part[tid] = s; __syncthreads();
    #pragma unroll
    for (int off = 1; off < 1024; off <<= 1) {
        int t2 = (tid >= off) ? part[tid - off] : 0;
        __syncthreads();
        part[tid] += t2;
        __syncthreads();
    }
    const int pre = tid ? part[tid - 1] : 0;
    #pragma unroll
    for (int j = 0; j < 16; ++j) {
        int i = base + j;
        if (i < N) {
            int st = pre + (j ? loc[j - 1] : 0);
            row_start[i] = st;
            cursor[i]    = st;
            if (i == N - 1) row_start[N] = pre + loc[j];
        }
    }
}

__global__ void csr_fill(const int* __restrict__ esrc, const int* __restrict__ edst,
                         int E, int Etot, int* __restrict__ cursor,
                         int* __restrict__ src_perm) {
    int e = blockIdx.x * blockDim.x + threadIdx.x;
    if (e >= Etot) return;
    int s, d;
    if (e < E) { s = esrc[e]; d = edst[e]; }
    else       { s = d = e - E; }
    int pos = atomicAdd(&cursor[d], 1);
    src_perm[pos] = s;
}

// ---------------------------------------------------------------------------
// Fused GATv2 edge phase, gather form, fp16 features, single gather per edge.
// One wave per dst node. xlr holds [xl | xr] per row (stride 2*HC).
// ---------------------------------------------------------------------------
template<int LOG2C>
__global__ __launch_bounds__(256) void gat_agg(
        const _Float16* __restrict__ xlr,
        const float* __restrict__ att, const float* __restrict__ bias,
        const int* __restrict__ row_start, const int* __restrict__ src_perm,
        int N, float* __restrict__ out) {
    constexpr int HC  = 4 << LOG2C;     // 512 / 256 / 128
    constexpr int R   = HC / 64;        // 8 / 4 / 2 channels per lane
    constexpr int STR = 2 * HC;
    constexpr int CAP = 8;
    using hvec = typename HV<R>::T;

    const int widx = threadIdx.x >> 6;
    const int lane = threadIdx.x & 63;
    const int dst  = blockIdx.x * 4 + widx;
    if (dst >= N) return;

    const int base = lane * R;
    float xrv[R], attv[R], acc[R];
    {
        hvec xv = *(const hvec*)&xlr[(size_t)dst * STR + HC + base];
        #pragma unroll
        for (int it = 0; it < R; ++it) {
            xrv[it]  = (float)xv[it];
            attv[it] = att[base + it];
            acc[it]  = 0.f;
        }
    }

    float m = -INFINITY, z = 0.f;
    const int start = row_start[dst], end = row_start[dst + 1];

    for (int cs = start; cs < end; cs += CAP) {
        const int cnt = min(CAP, end - cs);
        hvec  rows[CAP];
        float lg[CAP];
        float cmax = -INFINITY;
        #pragma unroll
        for (int k = 0; k < CAP; ++k) {
            if (k < cnt) {
                int src = __builtin_amdgcn_readfirstlane(src_perm[cs + k]);
                rows[k] = *(const hvec*)&xlr[(size_t)src * STR + base];
                float a = 0.f;
                #pragma unroll
                for (int it = 0; it < R; ++it) {
                    float v = (float)rows[k][it] + xrv[it];
                    v = v > 0.f ? v : 0.2f * v;
                    a += v * attv[it];
                }
                #pragma unroll
                for (int s = 1; s < 16; s <<= 1) a += __shfl_xor(a, s);
                lg[k] = a;
                cmax = fmaxf(cmax, a);
            }
        }
        float nm = fmaxf(m, cmax);
        float sc = __expf(m - nm);
        z *= sc;
        #pragma unroll
        for (int it = 0; it < R; ++it) acc[it] *= sc;
        m = nm;
        #pragma unroll
        for (int k = 0; k < CAP; ++k) {
            if (k < cnt) {
                float p = __expf(lg[k] - m);
                z += p;
                #pragma unroll
                for (int it = 0; it < R; ++it) acc[it] += p * (float)rows[k][it];
            }
        }
    }

    const float inv = 1.f / (z + 1e-16f);
    float ov[R];
    #pragma unroll
    for (int it = 0; it < R; ++it) ov[it] = acc[it] * inv + bias[base + it];
    float* po = out + (size_t)dst * HC + base;
    if constexpr (R == 8) {
        *(float4*)po       = make_float4(ov[0], ov[1], ov[2], ov[3]);
        *(float4*)(po + 4) = make_float4(ov[4], ov[5], ov[6], ov[7]);
    } else if constexpr (R == 4) {
        *(float4*)po = make_float4(ov[0], ov[1], ov[2], ov[3]);
    } else {
        *(float2*)po = make_float2(ov[0], ov[1]);
    }
}

// ---------------------------------------------------------------------------
// GraphNorm stats + per-channel affine coefficients (norm applied fused
// downstream: next GEMM's staging, or attn_pool).
// ---------------------------------------------------------------------------
__global__ __launch_bounds__(64) void colstats(const float* __restrict__ x, int HC,
                                               float* __restrict__ s1, float* __restrict__ s2) {
    int c  = blockIdx.x * 64 + threadIdx.x;
    int r0 = blockIdx.y * 128;
    float a = 0.f, b = 0.f;
    for (int r = r0; r < r0 + 128; ++r) {
        float v = x[(size_t)r * HC + c];
        a += v; b += v * v;
    }
    atomicAdd(&s1[c], a);
    atomicAdd(&s2[c], b);
}

__global__ void gn_finalize(const float* __restrict__ s1, const float* __restrict__ s2,
                            const float* __restrict__ w, const float* __restrict__ b,
                            const float* __restrict__ ms, int HC, float invN,
                            float* __restrict__ alpha, float* __restrict__ beta) {
    int c = blockIdx.x * blockDim.x + threadIdx.x;
    if (c >= HC) return;
    float mean = s1[c] * invN;
    float ex2  = s2[c] * invN;
    float a    = ms[c] * mean;
    float var  = ex2 - 2.f * a * mean + a * a;
    float al   = w[c] * rsqrtf(var + 1e-5f);
    alpha[c] = al;
    beta[c]  = b[c] - a * al;
}

// ---------------------------------------------------------------------------
__global__ __launch_bounds__(256) void gate_dot(const float* __restrict__ hid,
                                                const float* __restrict__ aW2,
                                                const float* __restrict__ ab2,
                                                float* __restrict__ gate, int N) {
    int w = (blockIdx.x * blockDim.x + threadIdx.x) >> 6;
    if (w >= N) return;
    int lane = threadIdx.x & 63;
    const float* ph = hid + (size_t)w * 128;
    float a = ph[lane] * aW2[lane] + ph[lane + 64] * aW2[lane + 64];
    #pragma unroll
    for (int s = 32; s; s >>= 1) a += __shfl_xor(a, s);
    if (lane == 0) gate[w] = a + ab2[0];
}

// Pooling over graphs; x is RAW layer-3 output, norm+relu applied inline.
__global__ __launch_bounds__(128) void attn_pool(const float* __restrict__ x,
                                                 const float* __restrict__ alpha,
                                                 const float* __restrict__ beta,
                                                 const float* __restrict__ gate,
                                                 const int* __restrict__ batch,
                                                 int N, float* __restrict__ out) {
    const int b   = blockIdx.x;
    const int tid = threadIdx.x;
    int lo, hi;
    { int l = 0, r = N; while (l < r) { int mid = (l + r) >> 1; if (batch[mid] < b) l = mid + 1; else r = mid; } lo = l; }
    { int l = lo, r = N; while (l < r) { int mid = (l + r) >> 1; if (batch[mid] < b + 1) l = mid + 1; else r = mid; } hi = l; }
    if (lo >= hi) { out[b * 128 + tid] = 0.f; return; }

    const float alc = alpha[tid], bec = beta[tid];
    __shared__ float red[128];
    float mx = -INFINITY;
    for (int n = lo + tid; n < hi; n += 128) mx = fmaxf(mx, gate[n]);
    red[tid] = mx; __syncthreads();
    for (int s = 64; s; s >>= 1) { if (tid < s) red[tid] = fmaxf(red[tid], red[tid + s]); __syncthreads(); }
    mx = red[0]; __syncthreads();

    float zs = 0.f;
    for (int n = lo + tid; n < hi; n += 128) zs += __expf(gate[n] - mx);
    red[tid] = zs; __syncthreads();
    for (int s = 64; s; s >>= 1) { if (tid < s) red[tid] += red[tid + s]; __syncthreads(); }
    zs = red[0];

    float acc = 0.f;
    for (int n = lo; n < hi; ++n) {
        float v = fmaxf(alc * x[(size_t)n * 128 + tid] + bec, 0.f);
        acc += __expf(gate[n] - mx) * v;
    }
    out[b * 128 + tid] = acc / (zs + 1e-16f);
}

// ---------------------------------------------------------------------------
extern "C" void kernel_launch(void* const* d_in, const int* in_sizes, int n_in,
                              void* d_out, int out_size, void* d_ws, size_t ws_size,
                              hipStream_t stream) {
    const float* x0  = (const float*)d_in[0];
    const int* edge  = (const int*)d_in[1];
    const int* batch = (const int*)d_in[2];
    const int N = in_sizes[2];
    const int E = in_sizes[1] / 2;
    const int Etot = E + N;
    const int dims[4] = {960, 512, 256, 128};

    const float* Wl[3]   = {(const float*)d_in[3],  (const float*)d_in[10], (const float*)d_in[17]};
    const float* Wr[3]   = {(const float*)d_in[4],  (const float*)d_in[11], (const float*)d_in[18]};
    const float* attp[3] = {(const float*)d_in[5],  (const float*)d_in[12], (const float*)d_in[19]};
    const float* bi[3]   = {(const float*)d_in[6],  (const float*)d_in[13], (const float*)d_in[20]};
    const float* gw[3]   = {(const float*)d_in[7],  (const float*)d_in[14], (const float*)d_in[21]};
    const float* gb[3]   = {(const float*)d_in[8],  (const float*)d_in[15], (const float*)d_in[22]};
    const float* gm[3]   = {(const float*)d_in[9],  (const float*)d_in[16], (const float*)d_in[23]};
    const float* aW1 = (const float*)d_in[24];
    const float* ab1 = (const float*)d_in[25];
    const float* aW2 = (const float*)d_in[26];
    const float* ab2 = (const float*)d_in[27];

    size_t off = 0;
    auto alloc = [&](size_t bytes) -> char* {
        char* p = (char*)d_ws + off;
        off += (bytes + 255) & ~(size_t)255;
        return p;
    };
    _Float16* xlr     = (_Float16*)alloc((size_t)N * 1024 * 2);  // [xl|xr] fp16
    float*   bufC     = (float*)alloc((size_t)N * 512 * 4);      // raw layer out
    int*     deg      = (int*)alloc((size_t)N * 4);
    int*     row_start= (int*)alloc((size_t)(N + 1) * 4);
    int*     cursor   = (int*)alloc((size_t)N * 4);
    int*     src_perm = (int*)alloc((size_t)Etot * 4);
    float*   s12      = (float*)alloc(3 * 1024 * 4);   // [layer][s1|s2][512]
    float*   alB      = (float*)alloc(3 * 512 * 4);
    float*   beB      = (float*)alloc(3 * 512 * 4);
    float*   gateB    = (float*)alloc((size_t)N * 4);
    _Float16* wt[3];
    for (int l = 0; l < 3; ++l)
        wt[l] = (_Float16*)alloc((size_t)dims[l] * (2 * dims[l + 1]) * 2);
    _Float16* awt = (_Float16*)alloc(128 * 128 * 2);
    float* poolhid = (float*)xlr;    // xlr dead at pooling time
    (void)ws_size; (void)n_in; (void)out_size;

    // ---- one-time weight transpose+convert (fp16, stacked [Wl^T;Wr^T]) ----
    for (int l = 0; l < 3; ++l) {
        int tot = dims[l] * dims[l + 1];
        conv_wf16<<<(tot + 255) / 256, 256, 0, stream>>>(Wl[l], Wr[l], wt[l], dims[l], dims[l + 1]);
    }
    conv_wf16<<<(128 * 128 + 255) / 256, 256, 0, stream>>>(aW1, nullptr, awt, 128, 128);

    // ---- CSR by dst ----
    hipMemsetAsync(deg, 0, (size_t)N * sizeof(int), stream);
    hipMemsetAsync(s12, 0, 3 * 1024 * sizeof(float), stream);
    csr_count<<<(Etot + 255) / 256, 256, 0, stream>>>(edge + E, E, Etot, deg);
    scan_deg<<<1, 1024, 0, stream>>>(deg, row_start, cursor, N);
    csr_fill<<<(Etot + 255) / 256, 256, 0, stream>>>(edge, edge + E, E, Etot,
                                                     cursor, src_perm);

    for (int l = 0; l < 3; ++l) {
        const int K = dims[l], HC = dims[l + 1];
        dim3 ggrid((2 * HC) / 128, N / 128);
        if (l == 0)
            mfma_gemm<false, false, false, _Float16><<<ggrid, 256, 0, stream>>>(
                x0, wt[0], nullptr, nullptr, nullptr, xlr, N, K, 2 * HC);
        else
            mfma_gemm<true, false, false, _Float16><<<ggrid, 256, 0, stream>>>(
                bufC, wt[l], alB + (l - 1) * 512, beB + (l - 1) * 512, nullptr,
                xlr, N, K, 2 * HC);

        const int agrid = (N + 3) / 4;
        if (l == 0)      gat_agg<7><<<agrid, 256, 0, stream>>>(xlr, attp[l], bi[l], row_start, src_perm, N, bufC);
        else if (l == 1) gat_agg<6><<<agrid, 256, 0, stream>>>(xlr, attp[l], bi[l], row_start, src_perm, N, bufC);
        else             gat_agg<5><<<agrid, 256, 0, stream>>>(xlr, attp[l], bi[l], row_start, src_perm, N, bufC);

        colstats<<<dim3(HC / 64, N / 128), 64, 0, stream>>>(bufC, HC, s12 + l * 1024, s12 + l * 1024 + 512);
        gn_finalize<<<(HC + 63) / 64, 64, 0, stream>>>(s12 + l * 1024, s12 + l * 1024 + 512,
                                                       gw[l], gb[l], gm[l], HC, 1.0f / N,
                                                       alB + l * 512, beB + l * 512);
    }

    // ---- attentional pooling (norm of layer 2 fused everywhere) ----
    mfma_gemm<true, true, true, float><<<dim3(1, N / 128), 256, 0, stream>>>(
        bufC, awt, alB + 1024, beB + 1024, ab1, poolhid, N, 128, 128);
    gate_dot<<<(N * 64 + 255) / 256, 256, 0, stream>>>(poolhid, aW2, ab2, gateB, N);
    attn_pool<<<64, 128, 0, stream>>>(bufC, alB + 1024, beB + 1024, gateB, batch, N, (float*)d_out);
}